// Round 1
// baseline (3380.041 us; speedup 1.0000x reference)
//
#include <hip/hip_runtime.h>
#include <hip/hip_bf16.h>
#include <math.h>

#define D 768
#define BQ 4
#define NQ 512
#define M_TOTAL (BQ*NQ)   // 2048
#define KSEL 64

#define TM 128
#define TV 128
#define KC 16

// ---------- row L2 inverse norms: one wave per row ----------
__global__ void row_invnorm_kernel(const float* __restrict__ x, float* __restrict__ inv, int rows)
{
    int wid  = (blockIdx.x * blockDim.x + threadIdx.x) >> 6;
    int lane = threadIdx.x & 63;
    if (wid >= rows) return;
    const float* r = x + (size_t)wid * D;
    float ss = 0.f;
    #pragma unroll
    for (int s = 0; s < 3; ++s) {
        float4 v = *reinterpret_cast<const float4*>(r + s*256 + lane*4);
        ss += v.x*v.x + v.y*v.y + v.z*v.z + v.w*v.w;
    }
    #pragma unroll
    for (int off = 32; off > 0; off >>= 1)
        ss += __shfl_xor(ss, off, 64);
    if (lane == 0) {
        float n = sqrtf(ss);
        inv[wid] = 1.0f / fmaxf(n, 1e-12f);
    }
}

// ---------- gq[b][d] = (1/NQ) * sum_n invq[b,n] * q[b,n,d] ----------
__global__ void compute_gq_kernel(const float* __restrict__ q, const float* __restrict__ invq,
                                  float* __restrict__ gq)
{
    int t = blockIdx.x * blockDim.x + threadIdx.x;
    if (t >= BQ*D) return;
    int b = t / D, d = t - b*D;
    float acc = 0.f;
    const float* qb = q + (size_t)b * NQ * D + d;
    const float* iq = invq + b*NQ;
    for (int n = 0; n < NQ; ++n)
        acc += iq[n] * qb[(size_t)n*D];
    gq[t] = acc * (1.0f/(float)NQ);
}

// ---------- main GEMM with fused row-max-pool ----------
// C[m,v] = Q[m,:].K[v,:] ; node partial[mtile][v] = invk[v] * max_{m in tile}(C[m,v]*invq[m])
__global__ __launch_bounds__(256)
void gemm_maxpool_kernel(const float* __restrict__ Q, const float* __restrict__ Kmat,
                         const float* __restrict__ invq, const float* __restrict__ invk,
                         float* __restrict__ partial, int V)
{
    __shared__ float As[KC][TM+1];
    __shared__ float Bs[KC][TV+1];

    const int v0 = blockIdx.x * TV;
    const int m0 = blockIdx.y * TM;
    const int t  = threadIdx.x;
    const int tx = t & 15;   // v dir
    const int ty = t >> 4;   // m dir

    float acc[8][8];
    #pragma unroll
    for (int i = 0; i < 8; ++i)
        #pragma unroll
        for (int j = 0; j < 8; ++j)
            acc[i][j] = 0.f;

    for (int kk = 0; kk < D; kk += KC) {
        // stage A and B tiles (transposed into LDS), 2 float4 per thread each
        #pragma unroll
        for (int l = 0; l < 2; ++l) {
            int f   = t + l*256;        // 0..511
            int row = f >> 2;           // 0..127
            int kp  = (f & 3) * 4;      // 0,4,8,12
            float4 a = *reinterpret_cast<const float4*>(Q + (size_t)(m0+row)*D + kk + kp);
            As[kp+0][row] = a.x; As[kp+1][row] = a.y;
            As[kp+2][row] = a.z; As[kp+3][row] = a.w;
            int vrow = v0 + row;
            float4 bv;
            if (vrow < V) bv = *reinterpret_cast<const float4*>(Kmat + (size_t)vrow*D + kk + kp);
            else          bv = make_float4(0.f,0.f,0.f,0.f);
            Bs[kp+0][row] = bv.x; Bs[kp+1][row] = bv.y;
            Bs[kp+2][row] = bv.z; Bs[kp+3][row] = bv.w;
        }
        __syncthreads();
        #pragma unroll
        for (int k = 0; k < KC; ++k) {
            float a[8], b[8];
            #pragma unroll
            for (int i = 0; i < 8; ++i) a[i] = As[k][ty*8+i];
            #pragma unroll
            for (int j = 0; j < 8; ++j) b[j] = Bs[k][tx*8+j];
            #pragma unroll
            for (int i = 0; i < 8; ++i)
                #pragma unroll
                for (int j = 0; j < 8; ++j)
                    acc[i][j] += a[i]*b[j];
        }
        __syncthreads();
    }

    // per-thread max over its 8 rows (scaled by invq)
    float tmax[8];
    #pragma unroll
    for (int j = 0; j < 8; ++j) tmax[j] = -INFINITY;
    #pragma unroll
    for (int i = 0; i < 8; ++i) {
        float s = invq[m0 + ty*8 + i];
        #pragma unroll
        for (int j = 0; j < 8; ++j)
            tmax[j] = fmaxf(tmax[j], acc[i][j]*s);
    }

    // reduce across ty via LDS (reuse As)
    float* red = &As[0][0];   // 16*128 floats needed, have 16*129
    #pragma unroll
    for (int j = 0; j < 8; ++j) red[ty*TV + tx*8 + j] = tmax[j];
    __syncthreads();
    if (t < TV) {
        float m = red[t];
        #pragma unroll
        for (int y = 1; y < 16; ++y) m = fmaxf(m, red[y*TV + t]);
        int v = v0 + t;
        if (v < V) partial[(size_t)blockIdx.y * V + v] = m * invk[v];
    }
}

// ---------- fused: node max over mtiles + graph sim + blend ----------
__global__ void fused_sim_kernel(const float* __restrict__ Kmat, const float* __restrict__ invk,
                                 const float* __restrict__ gq, const float* __restrict__ partial,
                                 const float* __restrict__ alpha_raw,
                                 float* __restrict__ out_fused, float* __restrict__ out_alpha, int V)
{
    int wib  = threadIdx.x >> 6;
    int lane = threadIdx.x & 63;
    float alpha = 1.0f / (1.0f + expf(-alpha_raw[0]));
    if (blockIdx.x == 0 && threadIdx.x == 0) out_alpha[0] = alpha;
    int v = blockIdx.x * 4 + wib;
    if (v >= V) return;
    const float* kr = Kmat + (size_t)v * D;
    float accb[BQ] = {0.f,0.f,0.f,0.f};
    #pragma unroll
    for (int s = 0; s < 3; ++s) {
        float4 kv = *reinterpret_cast<const float4*>(kr + s*256 + lane*4);
        #pragma unroll
        for (int b = 0; b < BQ; ++b) {
            float4 gv = *reinterpret_cast<const float4*>(gq + b*D + s*256 + lane*4);
            accb[b] += gv.x*kv.x + gv.y*kv.y + gv.z*kv.z + gv.w*kv.w;
        }
    }
    #pragma unroll
    for (int b = 0; b < BQ; ++b)
        #pragma unroll
        for (int off = 32; off > 0; off >>= 1)
            accb[b] += __shfl_xor(accb[b], off, 64);
    if (lane < BQ) {
        int b = lane;
        float node = partial[(size_t)(b*4+0)*V + v];
        #pragma unroll
        for (int i = 1; i < 4; ++i)
            node = fmaxf(node, partial[(size_t)(b*4+i)*V + v]);
        float graph = accb[b] * invk[v];
        out_fused[(size_t)b*V + v] = alpha*node + (1.0f-alpha)*graph;
    }
}

// ---------- per-batch top-64 (iterative argmax) + gather ----------
__global__ __launch_bounds__(1024)
void topk_gather_kernel(const float* __restrict__ fused, const float* __restrict__ Kmat,
                        float* __restrict__ scratch, float* __restrict__ out_sel,
                        float* __restrict__ out_idx, int V)
{
    int b = blockIdx.x;
    int t = threadIdx.x;
    const float* row = fused + (size_t)b*V;
    float* s = scratch + (size_t)b*V;
    for (int i = t; i < V; i += 1024) s[i] = row[i];
    __syncthreads();

    __shared__ float swv[16];
    __shared__ int   swi[16];
    __shared__ int   besti_s;
    int lane = t & 63, wid = t >> 6;

    for (int j = 0; j < KSEL; ++j) {
        float bv = -INFINITY; int bi = 0x7fffffff;
        for (int i = t; i < V; i += 1024) {
            float x = s[i];
            if (x > bv) { bv = x; bi = i; }
        }
        #pragma unroll
        for (int off = 32; off > 0; off >>= 1) {
            float ov = __shfl_xor(bv, off, 64);
            int   oi = __shfl_xor(bi, off, 64);
            if (ov > bv || (ov == bv && oi < bi)) { bv = ov; bi = oi; }
        }
        if (lane == 0) { swv[wid] = bv; swi[wid] = bi; }
        __syncthreads();
        if (t == 0) {
            float Bv = swv[0]; int Bi = swi[0];
            for (int w = 1; w < 16; ++w)
                if (swv[w] > Bv || (swv[w] == Bv && swi[w] < Bi)) { Bv = swv[w]; Bi = swi[w]; }
            besti_s = Bi;
            out_idx[b*KSEL + j] = (float)Bi;
            s[Bi] = -INFINITY;
        }
        __syncthreads();
        int bi_f = besti_s;
        if (t < D) out_sel[((size_t)b*KSEL + j)*D + t] = Kmat[(size_t)bi_f*D + t];
        __syncthreads();
    }
}

extern "C" void kernel_launch(void* const* d_in, const int* in_sizes, int n_in,
                              void* d_out, int out_size, void* d_ws, size_t ws_size,
                              hipStream_t stream)
{
    const float* q         = (const float*)d_in[0];
    const float* kemb      = (const float*)d_in[1];
    const float* alpha_raw = (const float*)d_in[2];
    int V = in_sizes[1] / D;
    int Valign = (V + 255) & ~255;

    float* ws      = (float*)d_ws;
    float* invk    = ws;                       // V
    float* invq    = invk + Valign;            // 2048
    float* gq      = invq + M_TOTAL;           // BQ*D
    float* partial = gq + BQ*D;                // 16*V (stride V)
    float* scratch = partial + 16*(size_t)Valign; // BQ*V

    float* out_sel   = (float*)d_out;            // BQ*KSEL*D
    float* out_idx   = out_sel + BQ*KSEL*D;      // BQ*KSEL
    float* out_fused = out_idx + BQ*KSEL;        // BQ*V
    float* out_alpha = out_fused + (size_t)BQ*V; // 1

    row_invnorm_kernel<<<(V + 3)/4, 256, 0, stream>>>(kemb, invk, V);
    row_invnorm_kernel<<<(M_TOTAL + 3)/4, 256, 0, stream>>>(q, invq, M_TOTAL);
    compute_gq_kernel<<<(BQ*D + 255)/256, 256, 0, stream>>>(q, invq, gq);

    dim3 g((V + TV - 1)/TV, M_TOTAL/TM);
    gemm_maxpool_kernel<<<g, 256, 0, stream>>>(q, kemb, invq, invk, partial, V);

    fused_sim_kernel<<<(V + 3)/4, 256, 0, stream>>>(kemb, invk, gq, partial, alpha_raw,
                                                    out_fused, out_alpha, V);
    topk_gather_kernel<<<BQ, 1024, 0, stream>>>(out_fused, kemb, scratch, out_sel, out_idx, V);
}

// Round 2
// 1026.080 us; speedup vs baseline: 3.2941x; 3.2941x over previous
//
#include <hip/hip_runtime.h>
#include <hip/hip_bf16.h>
#include <math.h>

#define D 768
#define BQ 4
#define NQ 512
#define M_TOTAL (BQ*NQ)   // 2048
#define KSEL 64
#define BMT 128
#define BVT 128
#define NSTEP (D/32)      // 24

typedef short bf16x8 __attribute__((ext_vector_type(8)));
typedef float f32x4  __attribute__((ext_vector_type(4)));

// ---------- row L2 inverse norms: one wave per row ----------
__global__ void row_invnorm_kernel(const float* __restrict__ x, float* __restrict__ inv, int rows)
{
    int wid  = (blockIdx.x * blockDim.x + threadIdx.x) >> 6;
    int lane = threadIdx.x & 63;
    if (wid >= rows) return;
    const float* r = x + (size_t)wid * D;
    float ss = 0.f;
    #pragma unroll
    for (int s = 0; s < 3; ++s) {
        float4 v = *reinterpret_cast<const float4*>(r + s*256 + lane*4);
        ss += v.x*v.x + v.y*v.y + v.z*v.z + v.w*v.w;
    }
    #pragma unroll
    for (int off = 32; off > 0; off >>= 1)
        ss += __shfl_xor(ss, off, 64);
    if (lane == 0) {
        float n = sqrtf(ss);
        inv[wid] = 1.0f / fmaxf(n, 1e-12f);
    }
}

// ---------- gq[b][d] = (1/NQ) * sum_n invq[b,n] * q[b,n,d] ----------
__global__ void compute_gq_kernel(const float* __restrict__ q, const float* __restrict__ invq,
                                  float* __restrict__ gq)
{
    int t = blockIdx.x * blockDim.x + threadIdx.x;
    if (t >= BQ*D) return;
    int b = t / D, d = t - b*D;
    float acc = 0.f;
    const float* qb = q + (size_t)b * NQ * D + d;
    const float* iq = invq + b*NQ;
    for (int n = 0; n < NQ; ++n)
        acc += iq[n] * qb[(size_t)n*D];
    gq[t] = acc * (1.0f/(float)NQ);
}

// ---------- fp32 -> bf16 hi/lo split ----------
__device__ __forceinline__ void split1(float x, unsigned int& h, unsigned int& l)
{
    unsigned int u  = __float_as_uint(x);
    unsigned int hb = (u + 0x7fffu + ((u >> 16) & 1u)) & 0xffff0000u;  // RNE bf16
    h = hb >> 16;
    l = __float_as_uint(x - __uint_as_float(hb)) >> 16;                 // truncated residual
}

__device__ __forceinline__ void split8(float4 a, float4 b, uint4& hi, uint4& lo)
{
    unsigned int h0,h1,h2,h3,h4,h5,h6,h7, l0,l1,l2,l3,l4,l5,l6,l7;
    split1(a.x,h0,l0); split1(a.y,h1,l1); split1(a.z,h2,l2); split1(a.w,h3,l3);
    split1(b.x,h4,l4); split1(b.y,h5,l5); split1(b.z,h6,l6); split1(b.w,h7,l7);
    hi.x = h0 | (h1<<16); hi.y = h2 | (h3<<16); hi.z = h4 | (h5<<16); hi.w = h6 | (h7<<16);
    lo.x = l0 | (l1<<16); lo.y = l2 | (l3<<16); lo.z = l4 | (l5<<16); lo.w = l6 | (l7<<16);
}

// ---------- MFMA split-bf16 GEMM with fused row-max-pool ----------
// partial[mtile][v] = invk[v] * max_{m in tile}( (Q[m,:].K[v,:]) * invq[m] )
__global__ __launch_bounds__(256)
void mfma_gemm_maxpool(const float* __restrict__ Q, const float* __restrict__ Kmat,
                       const float* __restrict__ invq, const float* __restrict__ invk,
                       float* __restrict__ partial, int V, int Vp)
{
    // lds layout (ushort units): Ahi[0..4095] Alo[4096..] Bhi[8192..] Blo[12288..]
    __shared__ __align__(16) unsigned short lds[16384];   // 32 KiB

    const int t    = threadIdx.x;
    const int lane = t & 63;
    const int w    = t >> 6;          // 0..3
    const int wr   = w >> 1;          // m-dir wave
    const int wc   = w & 1;           // v-dir wave
    const int v0   = blockIdx.x * BVT;
    const int m0   = blockIdx.y * BMT;

    // ---- staging coords: thread covers row=t/2, 16 floats starting at (t&1)*16 ----
    const int srow = t >> 1;
    const int scol = (t & 1) * 16;
    const int c0   = (t & 1) * 2;                        // logical 8-elem chunk index
    const unsigned int ps0 = (c0     + (srow >> 1)) & 3; // physical slot (swizzle)
    const unsigned int ps1 = (c0 + 1 + (srow >> 1)) & 3;
    const unsigned int wO0 = srow*32 + ps0*8;
    const unsigned int wO1 = srow*32 + ps1*8;

    const float* Ap = Q + (size_t)(m0 + srow) * D + scol;
    int vrow = v0 + srow; if (vrow > V-1) vrow = V-1;     // clamp tail block
    const float* Bp = Kmat + (size_t)vrow * D + scol;

    // ---- fragment read offsets ----
    const int lr = lane & 15, kg = lane >> 4;
    const int arowb = wr*64 + lr;
    const int browb = wc*64 + lr;
    const unsigned int slotA = (kg + (arowb >> 1)) & 3;   // fm*16 shifts row by 16 -> slot invariant
    const unsigned int slotB = (kg + (browb >> 1)) & 3;
    const unsigned int offA = arowb*32 + slotA*8;
    const unsigned int offB = browb*32 + slotB*8;

    f32x4 acc[4][4];
    #pragma unroll
    for (int i = 0; i < 4; ++i)
        #pragma unroll
        for (int j = 0; j < 4; ++j)
            acc[i][j] = f32x4{0.f,0.f,0.f,0.f};

    float4 ra0,ra1,ra2,ra3, rb0,rb1,rb2,rb3;
    #define LOADSTEP(s_) do { \
        const float* ap_ = Ap + (s_)*32; const float* bp_ = Bp + (s_)*32; \
        ra0 = *(const float4*)(ap_);    ra1 = *(const float4*)(ap_+4); \
        ra2 = *(const float4*)(ap_+8);  ra3 = *(const float4*)(ap_+12); \
        rb0 = *(const float4*)(bp_);    rb1 = *(const float4*)(bp_+4); \
        rb2 = *(const float4*)(bp_+8);  rb3 = *(const float4*)(bp_+12); \
    } while(0)

    LOADSTEP(0);
    for (int s = 0; s < NSTEP; ++s) {
        uint4 ah0,al0, ah1,al1, bh0,bl0, bh1,bl1;
        split8(ra0,ra1, ah0,al0); split8(ra2,ra3, ah1,al1);
        split8(rb0,rb1, bh0,bl0); split8(rb2,rb3, bh1,bl1);
        __syncthreads();                     // all waves done reading previous tile
        *(uint4*)&lds[        wO0] = ah0;  *(uint4*)&lds[ 4096 + wO0] = al0;
        *(uint4*)&lds[        wO1] = ah1;  *(uint4*)&lds[ 4096 + wO1] = al1;
        *(uint4*)&lds[ 8192 + wO0] = bh0;  *(uint4*)&lds[12288 + wO0] = bl0;
        *(uint4*)&lds[ 8192 + wO1] = bh1;  *(uint4*)&lds[12288 + wO1] = bl1;
        if (s + 1 < NSTEP) LOADSTEP(s + 1);  // prefetch overlaps compute below
        __syncthreads();                     // tile ready

        bf16x8 Ah[4], Al[4], Bh[4], Bl[4];
        #pragma unroll
        for (int fm = 0; fm < 4; ++fm) {
            unsigned int o = offA + fm*512;
            Ah[fm] = *(const bf16x8*)&lds[o];
            Al[fm] = *(const bf16x8*)&lds[4096 + o];
        }
        #pragma unroll
        for (int fv = 0; fv < 4; ++fv) {
            unsigned int o = offB + fv*512;
            Bh[fv] = *(const bf16x8*)&lds[8192 + o];
            Bl[fv] = *(const bf16x8*)&lds[12288 + o];
        }
        #pragma unroll
        for (int fm = 0; fm < 4; ++fm)
            #pragma unroll
            for (int fv = 0; fv < 4; ++fv) {
                acc[fm][fv] = __builtin_amdgcn_mfma_f32_16x16x32_bf16(Ah[fm], Bh[fv], acc[fm][fv], 0,0,0);
                acc[fm][fv] = __builtin_amdgcn_mfma_f32_16x16x32_bf16(Ah[fm], Bl[fv], acc[fm][fv], 0,0,0);
                acc[fm][fv] = __builtin_amdgcn_mfma_f32_16x16x32_bf16(Al[fm], Bh[fv], acc[fm][fv], 0,0,0);
            }
    }
    #undef LOADSTEP

    // ---- epilogue: max over m (scaled by invq), cross-lane + cross-wave reduce ----
    __syncthreads();                        // done with tiles; overlay red on lds
    float* red = (float*)lds;               // [2][128]
    float iq[4][4];
    #pragma unroll
    for (int fm = 0; fm < 4; ++fm)
        #pragma unroll
        for (int r = 0; r < 4; ++r)
            iq[fm][r] = invq[m0 + wr*64 + fm*16 + kg*4 + r];
    #pragma unroll
    for (int fv = 0; fv < 4; ++fv) {
        float tm = -INFINITY;
        #pragma unroll
        for (int fm = 0; fm < 4; ++fm)
            #pragma unroll
            for (int r = 0; r < 4; ++r)
                tm = fmaxf(tm, acc[fm][fv][r] * iq[fm][r]);
        tm = fmaxf(tm, __shfl_xor(tm, 16, 64));
        tm = fmaxf(tm, __shfl_xor(tm, 32, 64));
        if (lane < 16) red[wr*128 + wc*64 + fv*16 + lane] = tm;
    }
    __syncthreads();
    if (t < 128) {
        int v = v0 + t;
        if (v < V)
            partial[(size_t)blockIdx.y * Vp + v] = fmaxf(red[t], red[128 + t]) * invk[v];
    }
}

// ---------- fused: node max over mtiles + graph sim + blend ----------
__global__ void fused_sim_kernel(const float* __restrict__ Kmat, const float* __restrict__ invk,
                                 const float* __restrict__ gq, const float* __restrict__ partial,
                                 const float* __restrict__ alpha_raw,
                                 float* __restrict__ out_fused, float* __restrict__ out_alpha,
                                 int V, int Vp)
{
    int wib  = threadIdx.x >> 6;
    int lane = threadIdx.x & 63;
    float alpha = 1.0f / (1.0f + expf(-alpha_raw[0]));
    if (blockIdx.x == 0 && threadIdx.x == 0) out_alpha[0] = alpha;
    int v = blockIdx.x * 4 + wib;
    if (v >= V) return;
    const float* kr = Kmat + (size_t)v * D;
    float accb[BQ] = {0.f,0.f,0.f,0.f};
    #pragma unroll
    for (int s = 0; s < 3; ++s) {
        float4 kv = *reinterpret_cast<const float4*>(kr + s*256 + lane*4);
        #pragma unroll
        for (int b = 0; b < BQ; ++b) {
            float4 gv = *reinterpret_cast<const float4*>(gq + b*D + s*256 + lane*4);
            accb[b] += gv.x*kv.x + gv.y*kv.y + gv.z*kv.z + gv.w*kv.w;
        }
    }
    #pragma unroll
    for (int b = 0; b < BQ; ++b)
        #pragma unroll
        for (int off = 32; off > 0; off >>= 1)
            accb[b] += __shfl_xor(accb[b], off, 64);
    if (lane < BQ) {
        int b = lane;
        float node = partial[(size_t)(b*4+0)*Vp + v];
        #pragma unroll
        for (int i = 1; i < 4; ++i)
            node = fmaxf(node, partial[(size_t)(b*4+i)*Vp + v]);
        float graph = accb[b] * invk[v];
        out_fused[(size_t)b*V + v] = alpha*node + (1.0f-alpha)*graph;
    }
}

// ---------- per-batch top-64 with cached per-thread chunk maxima + gather ----------
__global__ __launch_bounds__(1024)
void topk_gather_kernel(const float* __restrict__ fused, const float* __restrict__ Kmat,
                        float* __restrict__ scratch, float* __restrict__ out_sel,
                        float* __restrict__ out_idx, int V, int Vp)
{
    const int b = blockIdx.x, t = threadIdx.x;
    const int lane = t & 63, wid = t >> 6;
    const float* row = fused + (size_t)b * V;
    float* s = scratch + (size_t)b * Vp;
    for (int i = t; i < V; i += 1024) s[i] = row[i];
    __syncthreads();

    const int CH = (V + 1023) / 1024;       // 50
    const int lo = t * CH;
    const int hi = min(V, lo + CH);
    float lmax = -INFINITY; int lidx = 0x7fffffff;
    for (int i = lo; i < hi; ++i) { float x = s[i]; if (x > lmax) { lmax = x; lidx = i; } }

    __shared__ float swv[16];
    __shared__ int   swi[16];
    __shared__ int   sbest;

    for (int j = 0; j < KSEL; ++j) {
        float v = lmax; int id = lidx;
        #pragma unroll
        for (int off = 32; off > 0; off >>= 1) {
            float ov = __shfl_xor(v, off, 64);
            int   oi = __shfl_xor(id, off, 64);
            if (ov > v || (ov == v && oi < id)) { v = ov; id = oi; }
        }
        if (lane == 0) { swv[wid] = v; swi[wid] = id; }
        __syncthreads();
        if (t == 0) {
            float bv = swv[0]; int bi = swi[0];
            for (int x = 1; x < 16; ++x)
                if (swv[x] > bv || (swv[x] == bv && swi[x] < bi)) { bv = swv[x]; bi = swi[x]; }
            sbest = bi;
            out_idx[b*KSEL + j] = (float)bi;
        }
        __syncthreads();
        const int sel = sbest;
        if (sel >= lo && sel < hi) {                 // owner removes + rescans its 50 elems
            s[sel] = -INFINITY;
            lmax = -INFINITY; lidx = 0x7fffffff;
            for (int i = lo; i < hi; ++i) { float x = s[i]; if (x > lmax) { lmax = x; lidx = i; } }
        }
        if (t < 192) {                               // gather selected key row (768 f32)
            float4 kv = *reinterpret_cast<const float4*>(&Kmat[(size_t)sel * D + t*4]);
            *reinterpret_cast<float4*>(&out_sel[((size_t)b*KSEL + j)*D + t*4]) = kv;
        }
    }
}

extern "C" void kernel_launch(void* const* d_in, const int* in_sizes, int n_in,
                              void* d_out, int out_size, void* d_ws, size_t ws_size,
                              hipStream_t stream)
{
    const float* q         = (const float*)d_in[0];
    const float* kemb      = (const float*)d_in[1];
    const float* alpha_raw = (const float*)d_in[2];
    int V  = in_sizes[1] / D;
    int Vp = (V + 127) & ~127;

    float* ws      = (float*)d_ws;
    float* invk    = ws;                          // Vp
    float* invq    = invk + Vp;                   // M_TOTAL
    float* gq      = invq + M_TOTAL;              // BQ*D
    float* partial = gq + BQ*D;                   // 16*Vp
    float* scratch = partial + (size_t)16*Vp;     // BQ*Vp

    float* out_sel   = (float*)d_out;             // BQ*KSEL*D
    float* out_idx   = out_sel + BQ*KSEL*D;       // BQ*KSEL
    float* out_fused = out_idx + BQ*KSEL;         // BQ*V
    float* out_alpha = out_fused + (size_t)BQ*V;  // 1

    row_invnorm_kernel<<<(V + 3)/4, 256, 0, stream>>>(kemb, invk, V);
    row_invnorm_kernel<<<(M_TOTAL + 3)/4, 256, 0, stream>>>(q, invq, M_TOTAL);
    compute_gq_kernel<<<(BQ*D + 255)/256, 256, 0, stream>>>(q, invq, gq);

    dim3 g(Vp / BVT, M_TOTAL / BMT);
    mfma_gemm_maxpool<<<g, 256, 0, stream>>>(q, kemb, invq, invk, partial, V, Vp);

    fused_sim_kernel<<<(V + 3)/4, 256, 0, stream>>>(kemb, invk, gq, partial, alpha_raw,
                                                    out_fused, out_alpha, V, Vp);
    topk_gather_kernel<<<BQ, 1024, 0, stream>>>(out_fused, kemb, scratch, out_sel, out_idx, V, Vp);
}

// Round 3
// 810.854 us; speedup vs baseline: 4.1685x; 1.2654x over previous
//
#include <hip/hip_runtime.h>
#include <hip/hip_bf16.h>
#include <math.h>

#define D 768
#define BQ 4
#define NQ 512
#define M_TOTAL (BQ*NQ)   // 2048
#define KSEL 64

typedef short bf16x8 __attribute__((ext_vector_type(8)));
typedef float f32x4  __attribute__((ext_vector_type(4)));

// ---------- fp32 -> bf16 hi/lo split ----------
__device__ __forceinline__ void split1(float x, unsigned int& h, unsigned int& l)
{
    unsigned int u  = __float_as_uint(x);
    unsigned int hb = (u + 0x7fffu + ((u >> 16) & 1u)) & 0xffff0000u;  // RNE bf16
    h = hb >> 16;
    l = __float_as_uint(x - __uint_as_float(hb)) >> 16;                 // truncated residual
}

// =====================================================================
// FAST PATH
// =====================================================================

// ---------- fused: L2 inv-norm + hi/lo bf16 split, one wave per row ----------
// dst layout: sp[r][0][0..767] = hi plane, sp[r][1][0..767] = lo plane (ushort)
__global__ void split_invnorm_kernel(const float* __restrict__ x, unsigned short* __restrict__ sp,
                                     float* __restrict__ inv, int rows_src, int rows_dst)
{
    int r    = (blockIdx.x * blockDim.x + threadIdx.x) >> 6;
    int lane = threadIdx.x & 63;
    if (r >= rows_dst) return;
    int src = r < rows_src ? r : rows_src - 1;      // clamp pad rows
    const float* row = x + (size_t)src * D;
    unsigned short* dh = sp + (size_t)r * (2*D);
    unsigned short* dl = dh + D;
    float ss = 0.f;
    #pragma unroll
    for (int s = 0; s < 3; ++s) {
        float4 v = *reinterpret_cast<const float4*>(row + s*256 + lane*4);
        ss += v.x*v.x + v.y*v.y + v.z*v.z + v.w*v.w;
        unsigned int h0,h1,h2,h3,l0,l1,l2,l3;
        split1(v.x,h0,l0); split1(v.y,h1,l1); split1(v.z,h2,l2); split1(v.w,h3,l3);
        ushort4 hv = make_ushort4((unsigned short)h0,(unsigned short)h1,(unsigned short)h2,(unsigned short)h3);
        ushort4 lv = make_ushort4((unsigned short)l0,(unsigned short)l1,(unsigned short)l2,(unsigned short)l3);
        *reinterpret_cast<ushort4*>(dh + s*256 + lane*4) = hv;
        *reinterpret_cast<ushort4*>(dl + s*256 + lane*4) = lv;
    }
    #pragma unroll
    for (int off = 32; off > 0; off >>= 1)
        ss += __shfl_xor(ss, off, 64);
    if (lane == 0 && r < rows_src)
        inv[r] = 1.0f / fmaxf(sqrtf(ss), 1e-12f);
}

// ---------- pipelined split-bf16 MFMA GEMM, fused max+sum epilogues ----------
// BM=256 (m), BN=128 (v), BK=32, 8 waves (4M x 2N), wave tile 64x64.
// LDS slot: A 256 rows x 128B (hi 32k | lo 32k, XOR-swizzled 16B chunks) = 32KB
//           B 128 rows x 128B = 16KB ; ring of 3 slots = 144KB dynamic LDS.
#define GBM 256
#define GBN 128
#define GBK 32
#define GNT (D/GBK)     // 24
#define SLOT_A 32768
#define SLOT_SZ 49152

__device__ __forceinline__ void gload16(const unsigned short* g, char* l)
{
    __builtin_amdgcn_global_load_lds((const __attribute__((address_space(1))) void*)g,
                                     (__attribute__((address_space(3))) void*)l, 16, 0, 0);
}

__global__ __launch_bounds__(512, 2)
void fast_gemm(const unsigned short* __restrict__ Qsp, const unsigned short* __restrict__ Ksp,
               const float* __restrict__ invq, float* __restrict__ pmax, float* __restrict__ psum,
               int Vp, int gx)
{
    extern __shared__ char smem[];

    const int t    = threadIdx.x;
    const int lane = t & 63;
    const int w    = t >> 6;         // 0..7
    const int wr   = w >> 1;         // 0..3 (m)
    const int wc   = w & 1;          // 0..1 (v)

    // XCD-aware swizzle, m-dim fastest (8 consecutive u share one K panel)
    int lid = blockIdx.x;
    int u   = (lid & 7) * gx + (lid >> 3);
    const int by = u & 7;
    const int bx = u >> 3;
    const int m0 = by * GBM;
    const int v0 = bx * GBN;

    // ---- staging: per-lane pre-swizzled global source ----
    const int lrow = lane >> 3;                    // dest row within 8-row group
    const int cc   = (lane & 7) ^ lrow;            // logical chunk at this lane's slot
    const size_t goff = (size_t)lrow * (2*D) + (size_t)(cc >> 2) * D + (size_t)(cc & 3) * 8;

    const unsigned short* gA = Qsp + (size_t)m0 * (2*D) + goff;
    const unsigned short* gB = Ksp + (size_t)v0 * (2*D) + goff;

    #define STAGE(k0_, slot_) do {                                        \
        const unsigned short* ga_ = gA + (k0_);                           \
        char* la_ = (slot_);                                              \
        _Pragma("unroll")                                                 \
        for (int j = 0; j < 4; ++j) {                                     \
            int ii = (w << 2) + j;                                        \
            gload16(ga_ + (size_t)ii * 8 * (2*D), la_ + ii*1024);         \
        }                                                                 \
        const unsigned short* gb_ = gB + (k0_);                           \
        char* lb_ = (slot_) + SLOT_A;                                     \
        _Pragma("unroll")                                                 \
        for (int j = 0; j < 2; ++j) {                                     \
            int ii = (w << 1) + j;                                        \
            gload16(gb_ + (size_t)ii * 8 * (2*D), lb_ + ii*1024);         \
        }                                                                 \
    } while (0)

    // ---- fragment read offsets (swizzle matches staging) ----
    const int l15 = lane & 15, kg = lane >> 4;
    const int swz_hi = ((kg)     ^ (lane & 7)) * 16;
    const int swz_lo = ((4 + kg) ^ (lane & 7)) * 16;
    const int offAhi = (wr*64 + l15)*128 + swz_hi;
    const int offAlo = (wr*64 + l15)*128 + swz_lo;
    const int offBhi = (wc*64 + l15)*128 + swz_hi;
    const int offBlo = (wc*64 + l15)*128 + swz_lo;

    f32x4 acc[4][4];
    #pragma unroll
    for (int i = 0; i < 4; ++i)
        #pragma unroll
        for (int j = 0; j < 4; ++j)
            acc[i][j] = f32x4{0.f,0.f,0.f,0.f};

    char* s0 = smem;
    char* s1 = smem + SLOT_SZ;
    char* s2 = smem + 2*SLOT_SZ;
    STAGE(0,   s0);
    STAGE(GBK, s1);
    char *sc = s0, *sn = s1, *ss = s2;

    #define COMPUTE(sl_) do {                                                   \
        const char* sA_ = (sl_);                                                \
        const char* sB_ = (sl_) + SLOT_A;                                       \
        bf16x8 Ah[4], Al[4], Bh[4], Bl[4];                                      \
        _Pragma("unroll")                                                       \
        for (int f = 0; f < 4; ++f) {                                           \
            Ah[f] = *(const bf16x8*)(sA_ + offAhi + f*2048);                    \
            Al[f] = *(const bf16x8*)(sA_ + offAlo + f*2048);                    \
            Bh[f] = *(const bf16x8*)(sB_ + offBhi + f*2048);                    \
            Bl[f] = *(const bf16x8*)(sB_ + offBlo + f*2048);                    \
        }                                                                       \
        _Pragma("unroll")                                                       \
        for (int fm = 0; fm < 4; ++fm)                                          \
            _Pragma("unroll")                                                   \
            for (int fn = 0; fn < 4; ++fn) {                                    \
                acc[fm][fn] = __builtin_amdgcn_mfma_f32_16x16x32_bf16(Ah[fm], Bh[fn], acc[fm][fn], 0,0,0); \
                acc[fm][fn] = __builtin_amdgcn_mfma_f32_16x16x32_bf16(Ah[fm], Bl[fn], acc[fm][fn], 0,0,0); \
                acc[fm][fn] = __builtin_amdgcn_mfma_f32_16x16x32_bf16(Al[fm], Bh[fn], acc[fm][fn], 0,0,0); \
            }                                                                   \
    } while (0)

    for (int T = 0; T < GNT - 1; ++T) {
        asm volatile("s_waitcnt vmcnt(6)" ::: "memory");   // tile T resident (counted, not 0)
        __builtin_amdgcn_s_barrier();
        if (T + 2 < GNT) STAGE((T + 2) * GBK, ss);
        COMPUTE(sc);
        char* tmp = sc; sc = sn; sn = ss; ss = tmp;
    }
    asm volatile("s_waitcnt vmcnt(0)" ::: "memory");       // last tile: full drain
    __builtin_amdgcn_s_barrier();
    COMPUTE(sc);

    // ---- epilogue: per-column max (node) and sum (graph), invq-scaled ----
    float iq[16];
    #pragma unroll
    for (int fm = 0; fm < 4; ++fm)
        #pragma unroll
        for (int r = 0; r < 4; ++r)
            iq[fm*4+r] = invq[m0 + wr*64 + fm*16 + kg*4 + r];

    float* redm = (float*)smem;        // [4][128]
    float* reds = redm + 512;          // [4][128]
    #pragma unroll
    for (int fn = 0; fn < 4; ++fn) {
        float pmv = -INFINITY, psv = 0.f;
        #pragma unroll
        for (int fm = 0; fm < 4; ++fm)
            #pragma unroll
            for (int r = 0; r < 4; ++r) {
                float x = acc[fm][fn][r] * iq[fm*4+r];
                pmv = fmaxf(pmv, x);
                psv += x;
            }
        pmv = fmaxf(pmv, __shfl_xor(pmv, 16, 64));
        pmv = fmaxf(pmv, __shfl_xor(pmv, 32, 64));
        psv += __shfl_xor(psv, 16, 64);
        psv += __shfl_xor(psv, 32, 64);
        if (lane < 16) {
            redm[wr*128 + wc*64 + fn*16 + l15] = pmv;
            reds[wr*128 + wc*64 + fn*16 + l15] = psv;
        }
    }
    __syncthreads();
    if (t < 128) {
        float m01 = fmaxf(redm[t], redm[128+t]);
        float m23 = fmaxf(redm[256+t], redm[384+t]);
        float sm  = reds[t] + reds[128+t] + reds[256+t] + reds[384+t];
        pmax[(size_t)by * Vp + v0 + t] = fmaxf(m01, m23);
        psum[(size_t)by * Vp + v0 + t] = sm;
    }
    #undef STAGE
    #undef COMPUTE
}

// ---------- blend: node max over batch tiles + graph from psum ----------
__global__ void blend_kernel(const float* __restrict__ pmax, const float* __restrict__ psum,
                             const float* __restrict__ invk, const float* __restrict__ alpha_raw,
                             float* __restrict__ out_fused, float* __restrict__ out_alpha,
                             int V, int Vp)
{
    int v = blockIdx.x * 256 + threadIdx.x;
    float alpha = 1.0f / (1.0f + expf(-alpha_raw[0]));
    if (blockIdx.x == 0 && threadIdx.x == 0) out_alpha[0] = alpha;
    if (v >= V) return;
    float ik = invk[v];
    #pragma unroll
    for (int b = 0; b < BQ; ++b) {
        float nm = fmaxf(pmax[(size_t)(2*b)*Vp + v], pmax[(size_t)(2*b+1)*Vp + v]) * ik;
        float gs = (psum[(size_t)(2*b)*Vp + v] + psum[(size_t)(2*b+1)*Vp + v]) * ik * (1.0f/(float)NQ);
        out_fused[(size_t)b*V + v] = alpha*nm + (1.0f-alpha)*gs;
    }
}

// ---------- per-batch top-64 (no gather inside) ----------
__global__ __launch_bounds__(1024)
void topk_kernel(const float* __restrict__ fused, float* __restrict__ scratch,
                 int* __restrict__ idxout, float* __restrict__ out_idx, int V, int Vp)
{
    const int b = blockIdx.x, t = threadIdx.x;
    const int lane = t & 63, wid = t >> 6;
    const float* row = fused + (size_t)b * V;
    float* s = scratch + (size_t)b * Vp;
    for (int i = t; i < V; i += 1024) s[i] = row[i];
    __syncthreads();

    const int CH = (V + 1023) >> 10;
    const int lo = t * CH;
    const int hi = min(V, lo + CH);
    float lmax = -INFINITY; int lidx = 0x7fffffff;
    for (int i = lo; i < hi; ++i) { float x = s[i]; if (x > lmax) { lmax = x; lidx = i; } }

    __shared__ float swv[16];
    __shared__ int   swi[16];
    __shared__ int   sbest;

    for (int j = 0; j < KSEL; ++j) {
        float v = lmax; int id = lidx;
        #pragma unroll
        for (int off = 32; off > 0; off >>= 1) {
            float ov = __shfl_xor(v, off, 64);
            int   oi = __shfl_xor(id, off, 64);
            if (ov > v || (ov == v && oi < id)) { v = ov; id = oi; }
        }
        if (lane == 0) { swv[wid] = v; swi[wid] = id; }
        __syncthreads();
        if (wid == 0) {
            float bv = (lane < 16) ? swv[lane] : -INFINITY;
            int   bi = (lane < 16) ? swi[lane] : 0x7fffffff;
            #pragma unroll
            for (int off = 8; off > 0; off >>= 1) {
                float ov = __shfl_xor(bv, off, 64);
                int   oi = __shfl_xor(bi, off, 64);
                if (ov > bv || (ov == bv && oi < bi)) { bv = ov; bi = oi; }
            }
            if (lane == 0) {
                sbest = bi;
                idxout[b*KSEL + j] = bi;
                out_idx[b*KSEL + j] = (float)bi;
            }
        }
        __syncthreads();
        const int sel = sbest;
        if (sel >= lo && sel < hi) {            // owner removes + rescans its chunk
            s[sel] = -INFINITY;
            lmax = -INFINITY; lidx = 0x7fffffff;
            for (int i = lo; i < hi; ++i) { float x = s[i]; if (x > lmax) { lmax = x; lidx = i; } }
        }
    }
}

// ---------- gather selected key rows ----------
__global__ void gather_kernel(const int* __restrict__ idx, const float* __restrict__ Kmat,
                              float* __restrict__ out_sel)
{
    int j = blockIdx.x & 63, b = blockIdx.x >> 6, t = threadIdx.x;
    int sel = idx[b*KSEL + j];
    float4 v = *reinterpret_cast<const float4*>(Kmat + (size_t)sel * D + t*4);
    *reinterpret_cast<float4*>(out_sel + ((size_t)(b*KSEL + j)) * D + t*4) = v;
}

// =====================================================================
// FALLBACK PATH (round-2, known-good) — used when ws_size is too small
// =====================================================================
#define BMT 128
#define BVT 128
#define NSTEP (D/32)

__global__ void row_invnorm_kernel(const float* __restrict__ x, float* __restrict__ inv, int rows)
{
    int wid  = (blockIdx.x * blockDim.x + threadIdx.x) >> 6;
    int lane = threadIdx.x & 63;
    if (wid >= rows) return;
    const float* r = x + (size_t)wid * D;
    float ss = 0.f;
    #pragma unroll
    for (int s = 0; s < 3; ++s) {
        float4 v = *reinterpret_cast<const float4*>(r + s*256 + lane*4);
        ss += v.x*v.x + v.y*v.y + v.z*v.z + v.w*v.w;
    }
    #pragma unroll
    for (int off = 32; off > 0; off >>= 1)
        ss += __shfl_xor(ss, off, 64);
    if (lane == 0) inv[wid] = 1.0f / fmaxf(sqrtf(ss), 1e-12f);
}

__global__ void compute_gq_kernel(const float* __restrict__ q, const float* __restrict__ invq,
                                  float* __restrict__ gq)
{
    int t = blockIdx.x * blockDim.x + threadIdx.x;
    if (t >= BQ*D) return;
    int b = t / D, d = t - b*D;
    float acc = 0.f;
    const float* qb = q + (size_t)b * NQ * D + d;
    const float* iq = invq + b*NQ;
    for (int n = 0; n < NQ; ++n)
        acc += iq[n] * qb[(size_t)n*D];
    gq[t] = acc * (1.0f/(float)NQ);
}

__device__ __forceinline__ void split8(float4 a, float4 b, uint4& hi, uint4& lo)
{
    unsigned int h0,h1,h2,h3,h4,h5,h6,h7, l0,l1,l2,l3,l4,l5,l6,l7;
    split1(a.x,h0,l0); split1(a.y,h1,l1); split1(a.z,h2,l2); split1(a.w,h3,l3);
    split1(b.x,h4,l4); split1(b.y,h5,l5); split1(b.z,h6,l6); split1(b.w,h7,l7);
    hi.x = h0 | (h1<<16); hi.y = h2 | (h3<<16); hi.z = h4 | (h5<<16); hi.w = h6 | (h7<<16);
    lo.x = l0 | (l1<<16); lo.y = l2 | (l3<<16); lo.z = l4 | (l5<<16); lo.w = l6 | (l7<<16);
}

__global__ __launch_bounds__(256)
void mfma_gemm_maxpool(const float* __restrict__ Q, const float* __restrict__ Kmat,
                       const float* __restrict__ invq, const float* __restrict__ invk,
                       float* __restrict__ partial, int V, int Vp)
{
    __shared__ __align__(16) unsigned short lds[16384];
    const int t    = threadIdx.x;
    const int lane = t & 63;
    const int w    = t >> 6;
    const int wr   = w >> 1;
    const int wc   = w & 1;
    const int v0   = blockIdx.x * BVT;
    const int m0   = blockIdx.y * BMT;

    const int srow = t >> 1;
    const int scol = (t & 1) * 16;
    const int c0   = (t & 1) * 2;
    const unsigned int ps0 = (c0     + (srow >> 1)) & 3;
    const unsigned int ps1 = (c0 + 1 + (srow >> 1)) & 3;
    const unsigned int wO0 = srow*32 + ps0*8;
    const unsigned int wO1 = srow*32 + ps1*8;

    const float* Ap = Q + (size_t)(m0 + srow) * D + scol;
    int vrow = v0 + srow; if (vrow > V-1) vrow = V-1;
    const float* Bp = Kmat + (size_t)vrow * D + scol;

    const int lr = lane & 15, kg = lane >> 4;
    const int arowb = wr*64 + lr;
    const int browb = wc*64 + lr;
    const unsigned int slotA = (kg + (arowb >> 1)) & 3;
    const unsigned int slotB = (kg + (browb >> 1)) & 3;
    const unsigned int offA = arowb*32 + slotA*8;
    const unsigned int offB = browb*32 + slotB*8;

    f32x4 acc[4][4];
    #pragma unroll
    for (int i = 0; i < 4; ++i)
        #pragma unroll
        for (int j = 0; j < 4; ++j)
            acc[i][j] = f32x4{0.f,0.f,0.f,0.f};

    float4 ra0,ra1,ra2,ra3, rb0,rb1,rb2,rb3;
    #define LOADSTEP(s_) do { \
        const float* ap_ = Ap + (s_)*32; const float* bp_ = Bp + (s_)*32; \
        ra0 = *(const float4*)(ap_);    ra1 = *(const float4*)(ap_+4); \
        ra2 = *(const float4*)(ap_+8);  ra3 = *(const float4*)(ap_+12); \
        rb0 = *(const float4*)(bp_);    rb1 = *(const float4*)(bp_+4); \
        rb2 = *(const float4*)(bp_+8);  rb3 = *(const float4*)(bp_+12); \
    } while(0)

    LOADSTEP(0);
    for (int s = 0; s < NSTEP; ++s) {
        uint4 ah0,al0, ah1,al1, bh0,bl0, bh1,bl1;
        split8(ra0,ra1, ah0,al0); split8(ra2,ra3, ah1,al1);
        split8(rb0,rb1, bh0,bl0); split8(rb2,rb3, bh1,bl1);
        __syncthreads();
        *(uint4*)&lds[        wO0] = ah0;  *(uint4*)&lds[ 4096 + wO0] = al0;
        *(uint4*)&lds[        wO1] = ah1;  *(uint4*)&lds[ 4096 + wO1] = al1;
        *(uint4*)&lds[ 8192 + wO0] = bh0;  *(uint4*)&lds[12288 + wO0] = bl0;
        *(uint4*)&lds[ 8192 + wO1] = bh1;  *(uint4*)&lds[12288 + wO1] = bl1;
        if (s + 1 < NSTEP) LOADSTEP(s + 1);
        __syncthreads();

        bf16x8 Ah[4], Al[4], Bh[4], Bl[4];
        #pragma unroll
        for (int fm = 0; fm < 4; ++fm) {
            unsigned int o = offA + fm*512;
            Ah[fm] = *(const bf16x8*)&lds[o];
            Al[fm] = *(const bf16x8*)&lds[4096 + o];
        }
        #pragma unroll
        for (int fv = 0; fv < 4; ++fv) {
            unsigned int o = offB + fv*512;
            Bh[fv] = *(const bf16x8*)&lds[8192 + o];
            Bl[fv] = *(const bf16x8*)&lds[12288 + o];
        }
        #pragma unroll
        for (int fm = 0; fm < 4; ++fm)
            #pragma unroll
            for (int fv = 0; fv < 4; ++fv) {
                acc[fm][fv] = __builtin_amdgcn_mfma_f32_16x16x32_bf16(Ah[fm], Bh[fv], acc[fm][fv], 0,0,0);
                acc[fm][fv] = __builtin_amdgcn_mfma_f32_16x16x32_bf16(Ah[fm], Bl[fv], acc[fm][fv], 0,0,0);
                acc[fm][fv] = __builtin_amdgcn_mfma_f32_16x16x32_bf16(Al[fm], Bh[fv], acc[fm][fv], 0,0,0);
            }
    }
    #undef LOADSTEP

    __syncthreads();
    float* red = (float*)lds;
    float iq[4][4];
    #pragma unroll
    for (int fm = 0; fm < 4; ++fm)
        #pragma unroll
        for (int r = 0; r < 4; ++r)
            iq[fm][r] = invq[m0 + wr*64 + fm*16 + kg*4 + r];
    #pragma unroll
    for (int fv = 0; fv < 4; ++fv) {
        float tm = -INFINITY;
        #pragma unroll
        for (int fm = 0; fm < 4; ++fm)
            #pragma unroll
            for (int r = 0; r < 4; ++r)
                tm = fmaxf(tm, acc[fm][fv][r] * iq[fm][r]);
        tm = fmaxf(tm, __shfl_xor(tm, 16, 64));
        tm = fmaxf(tm, __shfl_xor(tm, 32, 64));
        if (lane < 16) red[wr*128 + wc*64 + fv*16 + lane] = tm;
    }
    __syncthreads();
    if (t < 128) {
        int v = v0 + t;
        if (v < V)
            partial[(size_t)blockIdx.y * Vp + v] = fmaxf(red[t], red[128 + t]) * invk[v];
    }
}

__global__ void fused_sim_kernel(const float* __restrict__ Kmat, const float* __restrict__ invk,
                                 const float* __restrict__ gq, const float* __restrict__ partial,
                                 const float* __restrict__ alpha_raw,
                                 float* __restrict__ out_fused, float* __restrict__ out_alpha,
                                 int V, int Vp)
{
    int wib  = threadIdx.x >> 6;
    int lane = threadIdx.x & 63;
    float alpha = 1.0f / (1.0f + expf(-alpha_raw[0]));
    if (blockIdx.x == 0 && threadIdx.x == 0) out_alpha[0] = alpha;
    int v = blockIdx.x * 4 + wib;
    if (v >= V) return;
    const float* kr = Kmat + (size_t)v * D;
    float accb[BQ] = {0.f,0.f,0.f,0.f};
    #pragma unroll
    for (int s = 0; s < 3; ++s) {
        float4 kv = *reinterpret_cast<const float4*>(kr + s*256 + lane*4);
        #pragma unroll
        for (int b = 0; b < BQ; ++b) {
            float4 gv = *reinterpret_cast<const float4*>(gq + b*D + s*256 + lane*4);
            accb[b] += gv.x*kv.x + gv.y*kv.y + gv.z*kv.z + gv.w*kv.w;
        }
    }
    #pragma unroll
    for (int b = 0; b < BQ; ++b)
        #pragma unroll
        for (int off = 32; off > 0; off >>= 1)
            accb[b] += __shfl_xor(accb[b], off, 64);
    if (lane < BQ) {
        int b = lane;
        float node = partial[(size_t)(b*4+0)*Vp + v];
        #pragma unroll
        for (int i = 1; i < 4; ++i)
            node = fmaxf(node, partial[(size_t)(b*4+i)*Vp + v]);
        float graph = accb[b] * invk[v];
        out_fused[(size_t)b*V + v] = alpha*node + (1.0f-alpha)*graph;
    }
}

__global__ __launch_bounds__(1024)
void topk_gather_kernel(const float* __restrict__ fused, const float* __restrict__ Kmat,
                        float* __restrict__ scratch, float* __restrict__ out_sel,
                        float* __restrict__ out_idx, int V, int Vp)
{
    const int b = blockIdx.x, t = threadIdx.x;
    const int lane = t & 63, wid = t >> 6;
    const float* row = fused + (size_t)b * V;
    float* s = scratch + (size_t)b * Vp;
    for (int i = t; i < V; i += 1024) s[i] = row[i];
    __syncthreads();

    const int CH = (V + 1023) / 1024;
    const int lo = t * CH;
    const int hi = min(V, lo + CH);
    float lmax = -INFINITY; int lidx = 0x7fffffff;
    for (int i = lo; i < hi; ++i) { float x = s[i]; if (x > lmax) { lmax = x; lidx = i; } }

    __shared__ float swv[16];
    __shared__ int   swi[16];
    __shared__ int   sbest;

    for (int j = 0; j < KSEL; ++j) {
        float v = lmax; int id = lidx;
        #pragma unroll
        for (int off = 32; off > 0; off >>= 1) {
            float ov = __shfl_xor(v, off, 64);
            int   oi = __shfl_xor(id, off, 64);
            if (ov > v || (ov == v && oi < id)) { v = ov; id = oi; }
        }
        if (lane == 0) { swv[wid] = v; swi[wid] = id; }
        __syncthreads();
        if (t == 0) {
            float bv = swv[0]; int bi = swi[0];
            for (int x = 1; x < 16; ++x)
                if (swv[x] > bv || (swv[x] == bv && swi[x] < bi)) { bv = swv[x]; bi = swi[x]; }
            sbest = bi;
            out_idx[b*KSEL + j] = (float)bi;
        }
        __syncthreads();
        const int sel = sbest;
        if (sel >= lo && sel < hi) {
            s[sel] = -INFINITY;
            lmax = -INFINITY; lidx = 0x7fffffff;
            for (int i = lo; i < hi; ++i) { float x = s[i]; if (x > lmax) { lmax = x; lidx = i; } }
        }
        if (t < 192) {
            float4 kv = *reinterpret_cast<const float4*>(&Kmat[(size_t)sel * D + t*4]);
            *reinterpret_cast<float4*>(&out_sel[((size_t)b*KSEL + j)*D + t*4]) = kv;
        }
        __syncthreads();
    }
}

// =====================================================================
extern "C" void kernel_launch(void* const* d_in, const int* in_sizes, int n_in,
                              void* d_out, int out_size, void* d_ws, size_t ws_size,
                              hipStream_t stream)
{
    const float* q         = (const float*)d_in[0];
    const float* kemb      = (const float*)d_in[1];
    const float* alpha_raw = (const float*)d_in[2];
    int V = in_sizes[1] / D;

    float* out_sel   = (float*)d_out;
    float* out_idx   = out_sel + BQ*KSEL*D;
    float* out_fused = out_idx + BQ*KSEL;
    float* out_alpha = out_fused + (size_t)BQ*V;

    // ---------- fast-path workspace layout ----------
    size_t Vp = (size_t)((V + 255) & ~255);
    float* ws      = (float*)d_ws;
    float* invk    = ws;                               // Vp
    float* invq    = invk + Vp;                        // M_TOTAL
    float* pmax    = invq + M_TOTAL;                   // 8*Vp
    float* psum    = pmax + 8*Vp;                      // 8*Vp
    float* scratch = psum + 8*Vp;                      // 4*Vp
    int*   idxbuf  = (int*)(scratch + 4*Vp);           // 256
    unsigned short* Qsp = (unsigned short*)(idxbuf + 256);      // M_TOTAL*1536
    unsigned short* Ksp = Qsp + (size_t)M_TOTAL * (2*D);        // Vp*1536
    size_t need = (size_t)((char*)(Ksp + Vp*(2*D)) - (char*)d_ws);

    if (ws_size >= need) {
        // ---------- FAST PATH ----------
        split_invnorm_kernel<<<M_TOTAL/4, 256, 0, stream>>>(q, Qsp, invq, M_TOTAL, M_TOTAL);
        split_invnorm_kernel<<<(int)(Vp/4), 256, 0, stream>>>(kemb, Ksp, invk, V, (int)Vp);

        static int lds_attr_set = 0;
        (void)lds_attr_set;
        hipFuncSetAttribute(reinterpret_cast<const void*>(fast_gemm),
                            hipFuncAttributeMaxDynamicSharedMemorySize, 3*SLOT_SZ);

        int gx = (int)(Vp / GBN);
        fast_gemm<<<gx*8, 512, 3*SLOT_SZ, stream>>>(Qsp, Ksp, invq, pmax, psum, (int)Vp, gx);

        blend_kernel<<<(V + 255)/256, 256, 0, stream>>>(pmax, psum, invk, alpha_raw,
                                                        out_fused, out_alpha, V, (int)Vp);
        topk_kernel<<<BQ, 1024, 0, stream>>>(out_fused, scratch, idxbuf, out_idx, V, (int)Vp);
        gather_kernel<<<BQ*KSEL, 192, 0, stream>>>(idxbuf, kemb, out_sel);
    } else {
        // ---------- FALLBACK (round-2) ----------
        int Vp2 = (V + 127) & ~127;
        float* f_invk    = ws;
        float* f_invq    = f_invk + Vp2;
        float* f_gq      = f_invq + M_TOTAL;
        float* f_partial = f_gq + BQ*D;
        float* f_scratch = f_partial + (size_t)16*Vp2;

        row_invnorm_kernel<<<(V + 3)/4, 256, 0, stream>>>(kemb, f_invk, V);
        row_invnorm_kernel<<<(M_TOTAL + 3)/4, 256, 0, stream>>>(q, f_invq, M_TOTAL);
        compute_gq_kernel<<<(BQ*D + 255)/256, 256, 0, stream>>>(q, f_invq, f_gq);

        dim3 g(Vp2 / BVT, M_TOTAL / BMT);
        mfma_gemm_maxpool<<<g, 256, 0, stream>>>(q, kemb, f_invq, f_invk, f_partial, V, Vp2);

        fused_sim_kernel<<<(V + 3)/4, 256, 0, stream>>>(kemb, f_invk, f_gq, f_partial, alpha_raw,
                                                        out_fused, out_alpha, V, Vp2);
        topk_gather_kernel<<<BQ, 1024, 0, stream>>>(out_fused, kemb, f_scratch, out_sel, out_idx, V, Vp2);
    }
}

// Round 4
// 566.480 us; speedup vs baseline: 5.9667x; 1.4314x over previous
//
#include <hip/hip_runtime.h>
#include <hip/hip_bf16.h>
#include <math.h>

#define D 768
#define BQ 4
#define NQ 512
#define M_TOTAL (BQ*NQ)   // 2048
#define KSEL 64

typedef short bf16x8 __attribute__((ext_vector_type(8)));
typedef float f32x4  __attribute__((ext_vector_type(4)));

// ---------- fp32 -> bf16 hi/lo split ----------
__device__ __forceinline__ void split1(float x, unsigned int& h, unsigned int& l)
{
    unsigned int u  = __float_as_uint(x);
    unsigned int hb = (u + 0x7fffu + ((u >> 16) & 1u)) & 0xffff0000u;  // RNE bf16
    h = hb >> 16;
    l = __float_as_uint(x - __uint_as_float(hb)) >> 16;                 // truncated residual
}

// =====================================================================
// FAST PATH
// =====================================================================

// ---------- fused: L2 inv-norm + hi/lo bf16 split, one wave per row ----------
// dst layout: sp[r][0][0..767] = hi plane, sp[r][1][0..767] = lo plane (ushort)
__global__ void split_invnorm_kernel(const float* __restrict__ x, unsigned short* __restrict__ sp,
                                     float* __restrict__ inv, int rows_src, int rows_dst)
{
    int r    = (blockIdx.x * blockDim.x + threadIdx.x) >> 6;
    int lane = threadIdx.x & 63;
    if (r >= rows_dst) return;
    int src = r < rows_src ? r : rows_src - 1;      // clamp pad rows
    const float* row = x + (size_t)src * D;
    unsigned short* dh = sp + (size_t)r * (2*D);
    unsigned short* dl = dh + D;
    float ss = 0.f;
    #pragma unroll
    for (int s = 0; s < 3; ++s) {
        float4 v = *reinterpret_cast<const float4*>(row + s*256 + lane*4);
        ss += v.x*v.x + v.y*v.y + v.z*v.z + v.w*v.w;
        unsigned int h0,h1,h2,h3,l0,l1,l2,l3;
        split1(v.x,h0,l0); split1(v.y,h1,l1); split1(v.z,h2,l2); split1(v.w,h3,l3);
        ushort4 hv = make_ushort4((unsigned short)h0,(unsigned short)h1,(unsigned short)h2,(unsigned short)h3);
        ushort4 lv = make_ushort4((unsigned short)l0,(unsigned short)l1,(unsigned short)l2,(unsigned short)l3);
        *reinterpret_cast<ushort4*>(dh + s*256 + lane*4) = hv;
        *reinterpret_cast<ushort4*>(dl + s*256 + lane*4) = lv;
    }
    #pragma unroll
    for (int off = 32; off > 0; off >>= 1)
        ss += __shfl_xor(ss, off, 64);
    if (lane == 0 && r < rows_src)
        inv[r] = 1.0f / fmaxf(sqrtf(ss), 1e-12f);
}

// ---------- phased split-bf16 MFMA GEMM (m201-style), fused max+sum epilogues ----------
// BM=256 (m), BN=128 (v), BK=32, 8 waves (4M x 2N), wave tile 64x64.
// LDS slot: A 256 rows x 128B (hi|lo, XOR-swizzled 16B chunks) = 32KB ; B 128 rows = 16KB
// ring of 3 slots = 144KB dynamic LDS. Counted vmcnt(6), 4 phases x {2 barriers, lgkm0, setprio}.
#define GBM 256
#define GBN 128
#define GBK 32
#define GNT (D/GBK)     // 24
#define SLOT_A 32768
#define SLOT_SZ 49152

__device__ __forceinline__ void gload16(const unsigned short* g, char* l)
{
    __builtin_amdgcn_global_load_lds((const __attribute__((address_space(1))) void*)g,
                                     (__attribute__((address_space(3))) void*)l, 16, 0, 0);
}

__global__ __launch_bounds__(512, 2)
void fast_gemm(const unsigned short* __restrict__ Qsp, const unsigned short* __restrict__ Ksp,
               const float* __restrict__ invq, float* __restrict__ pmax, float* __restrict__ psum,
               int Vp, int gx)
{
    extern __shared__ char smem[];

    const int t    = threadIdx.x;
    const int lane = t & 63;
    const int w    = t >> 6;         // 0..7
    const int wr   = w >> 1;         // 0..3 (m)
    const int wc   = w & 1;          // 0..1 (v)

    // XCD-aware swizzle
    int lid = blockIdx.x;
    int u   = (lid & 7) * gx + (lid >> 3);
    const int by = u & 7;
    const int bx = u >> 3;
    const int m0 = by * GBM;
    const int v0 = bx * GBN;

    // ---- staging: per-lane pre-swizzled global source ----
    const int lrow = lane >> 3;
    const int cc   = (lane & 7) ^ lrow;
    const size_t goff = (size_t)lrow * (2*D) + (size_t)(cc >> 2) * D + (size_t)(cc & 3) * 8;

    const unsigned short* gA = Qsp + (size_t)m0 * (2*D) + goff;
    const unsigned short* gB = Ksp + (size_t)v0 * (2*D) + goff;

    #define STAGE_FULL(k0_, slot_) do {                                   \
        const unsigned short* ga_ = gA + (k0_);                           \
        char* la_ = (slot_);                                              \
        _Pragma("unroll")                                                 \
        for (int j = 0; j < 4; ++j) {                                     \
            int ii = (w << 2) + j;                                        \
            gload16(ga_ + (size_t)ii * 8 * (2*D), la_ + ii*1024);         \
        }                                                                 \
        const unsigned short* gb_ = gB + (k0_);                           \
        char* lb_ = (slot_) + SLOT_A;                                     \
        _Pragma("unroll")                                                 \
        for (int j = 0; j < 2; ++j) {                                     \
            int ii = (w << 1) + j;                                        \
            gload16(gb_ + (size_t)ii * 8 * (2*D), lb_ + ii*1024);         \
        }                                                                 \
    } while (0)

    #define STAGE_A2(k0_, slot_, j0_) do { if (st_) {                     \
        const unsigned short* ga_ = gA + (k0_);                           \
        char* la_ = (slot_);                                              \
        int ii0 = (w << 2) + (j0_);                                       \
        gload16(ga_ + (size_t)ii0 * 8 * (2*D), la_ + ii0*1024);           \
        int ii1 = ii0 + 1;                                                \
        gload16(ga_ + (size_t)ii1 * 8 * (2*D), la_ + ii1*1024);           \
    } } while (0)

    #define STAGE_B1(k0_, slot_, j_) do { if (st_) {                      \
        const unsigned short* gb_ = gB + (k0_);                           \
        char* lb_ = (slot_) + SLOT_A;                                     \
        int ii = (w << 1) + (j_);                                         \
        gload16(gb_ + (size_t)ii * 8 * (2*D), lb_ + ii*1024);             \
    } } while (0)

    // ---- fragment read offsets (swizzle matches staging) ----
    const int l15 = lane & 15, kg = lane >> 4;
    const int swz_hi = ((kg)     ^ (lane & 7)) * 16;
    const int swz_lo = ((4 + kg) ^ (lane & 7)) * 16;
    const int offAhi = (wr*64 + l15)*128 + swz_hi;
    const int offAlo = (wr*64 + l15)*128 + swz_lo;
    const int offBhi = (wc*64 + l15)*128 + swz_hi;
    const int offBlo = (wc*64 + l15)*128 + swz_lo;

    f32x4 acc[4][4];
    #pragma unroll
    for (int i = 0; i < 4; ++i)
        #pragma unroll
        for (int j = 0; j < 4; ++j)
            acc[i][j] = f32x4{0.f,0.f,0.f,0.f};

    char* s0 = smem;
    char* s1 = smem + SLOT_SZ;
    char* s2 = smem + 2*SLOT_SZ;
    STAGE_FULL(0,   s0);
    STAGE_FULL(GBK, s1);
    char *sc = s0, *sn = s1, *ss = s2;

    for (int T = 0; T < GNT; ++T) {
        const bool st_ = (T + 2 < GNT);
        const int  k2  = (T + 2) * GBK;
        const char* sA_ = sc;
        const char* sB_ = sc + SLOT_A;

        if (T < GNT - 1) asm volatile("s_waitcnt vmcnt(6)" ::: "memory");
        else             asm volatile("s_waitcnt vmcnt(0)" ::: "memory");
        __builtin_amdgcn_s_barrier();

        // ---- phase 0: all B frags + A row 0 ----
        bf16x8 Bh[4], Bl[4];
        #pragma unroll
        for (int f = 0; f < 4; ++f) {
            Bh[f] = *(const bf16x8*)(sB_ + offBhi + f*2048);
            Bl[f] = *(const bf16x8*)(sB_ + offBlo + f*2048);
        }
        bf16x8 Ah = *(const bf16x8*)(sA_ + offAhi);
        bf16x8 Al = *(const bf16x8*)(sA_ + offAlo);
        STAGE_A2(k2, ss, 0);
        __builtin_amdgcn_s_barrier();
        asm volatile("s_waitcnt lgkmcnt(0)" ::: "memory");
        __builtin_amdgcn_s_setprio(1);
        #pragma unroll
        for (int fn = 0; fn < 4; ++fn) {
            acc[0][fn] = __builtin_amdgcn_mfma_f32_16x16x32_bf16(Ah, Bh[fn], acc[0][fn], 0,0,0);
            acc[0][fn] = __builtin_amdgcn_mfma_f32_16x16x32_bf16(Ah, Bl[fn], acc[0][fn], 0,0,0);
            acc[0][fn] = __builtin_amdgcn_mfma_f32_16x16x32_bf16(Al, Bh[fn], acc[0][fn], 0,0,0);
        }
        __builtin_amdgcn_s_setprio(0);
        __builtin_amdgcn_s_barrier();

        // ---- phases 1..3: A row p ----
        #pragma unroll
        for (int p = 1; p < 4; ++p) {
            Ah = *(const bf16x8*)(sA_ + offAhi + p*2048);
            Al = *(const bf16x8*)(sA_ + offAlo + p*2048);
            if (p == 1)      STAGE_A2(k2, ss, 2);
            else if (p == 2) STAGE_B1(k2, ss, 0);
            else             STAGE_B1(k2, ss, 1);
            __builtin_amdgcn_s_barrier();
            asm volatile("s_waitcnt lgkmcnt(0)" ::: "memory");
            __builtin_amdgcn_s_setprio(1);
            #pragma unroll
            for (int fn = 0; fn < 4; ++fn) {
                acc[p][fn] = __builtin_amdgcn_mfma_f32_16x16x32_bf16(Ah, Bh[fn], acc[p][fn], 0,0,0);
                acc[p][fn] = __builtin_amdgcn_mfma_f32_16x16x32_bf16(Ah, Bl[fn], acc[p][fn], 0,0,0);
                acc[p][fn] = __builtin_amdgcn_mfma_f32_16x16x32_bf16(Al, Bh[fn], acc[p][fn], 0,0,0);
            }
            __builtin_amdgcn_s_setprio(0);
            __builtin_amdgcn_s_barrier();
        }
        char* tmp = sc; sc = sn; sn = ss; ss = tmp;
    }
    #undef STAGE_FULL
    #undef STAGE_A2
    #undef STAGE_B1

    // ---- epilogue: per-column max (node) and sum (graph), invq-scaled ----
    float iq[16];
    #pragma unroll
    for (int fm = 0; fm < 4; ++fm)
        #pragma unroll
        for (int r = 0; r < 4; ++r)
            iq[fm*4+r] = invq[m0 + wr*64 + fm*16 + kg*4 + r];

    float* redm = (float*)smem;        // [4][128]
    float* reds = redm + 512;          // [4][128]
    #pragma unroll
    for (int fn = 0; fn < 4; ++fn) {
        float pmv = -INFINITY, psv = 0.f;
        #pragma unroll
        for (int fm = 0; fm < 4; ++fm)
            #pragma unroll
            for (int r = 0; r < 4; ++r) {
                float x = acc[fm][fn][r] * iq[fm*4+r];
                pmv = fmaxf(pmv, x);
                psv += x;
            }
        pmv = fmaxf(pmv, __shfl_xor(pmv, 16, 64));
        pmv = fmaxf(pmv, __shfl_xor(pmv, 32, 64));
        psv += __shfl_xor(psv, 16, 64);
        psv += __shfl_xor(psv, 32, 64);
        if (lane < 16) {
            redm[wr*128 + wc*64 + fn*16 + l15] = pmv;
            reds[wr*128 + wc*64 + fn*16 + l15] = psv;
        }
    }
    __syncthreads();
    if (t < 128) {
        float m01 = fmaxf(redm[t], redm[128+t]);
        float m23 = fmaxf(redm[256+t], redm[384+t]);
        float sm  = reds[t] + reds[128+t] + reds[256+t] + reds[384+t];
        pmax[(size_t)by * Vp + v0 + t] = fmaxf(m01, m23);
        psum[(size_t)by * Vp + v0 + t] = sm;
    }
}

// ---------- blend: node max over batch tiles + graph from psum ----------
__global__ void blend_kernel(const float* __restrict__ pmax, const float* __restrict__ psum,
                             const float* __restrict__ invk, const float* __restrict__ alpha_raw,
                             float* __restrict__ out_fused, float* __restrict__ out_alpha,
                             int V, int Vp)
{
    int v = blockIdx.x * 256 + threadIdx.x;
    float alpha = 1.0f / (1.0f + expf(-alpha_raw[0]));
    if (blockIdx.x == 0 && threadIdx.x == 0) out_alpha[0] = alpha;
    if (v >= V) return;
    float ik = invk[v];
    #pragma unroll
    for (int b = 0; b < BQ; ++b) {
        float nm = fmaxf(pmax[(size_t)(2*b)*Vp + v], pmax[(size_t)(2*b+1)*Vp + v]) * ik;
        float gs = (psum[(size_t)(2*b)*Vp + v] + psum[(size_t)(2*b+1)*Vp + v]) * ik * (1.0f/(float)NQ);
        out_fused[(size_t)b*V + v] = alpha*nm + (1.0f-alpha)*gs;
    }
}

// ---------- per-batch top-64 via 4-pass radix select + bitonic order ----------
__device__ __forceinline__ unsigned int mono_map(float f)
{
    unsigned int u = __float_as_uint(f);
    return u ^ ((u & 0x80000000u) ? 0xFFFFFFFFu : 0x80000000u);
}

__global__ __launch_bounds__(1024)
void topk_radix_kernel(const float* __restrict__ fused,
                       int* __restrict__ idxout, float* __restrict__ out_idx, int V)
{
    const int b = blockIdx.x, t = threadIdx.x;
    const float* row = fused + (size_t)b * V;

    __shared__ unsigned int hist[256];
    __shared__ unsigned int sh_pref;
    __shared__ int sh_kneed;
    __shared__ unsigned int sh_nA, sh_nE;
    __shared__ unsigned long long key[64];
    __shared__ int eqIdx[256];

    unsigned int pref = 0;
    int kneed = KSEL;
    #pragma unroll
    for (int p = 24; p >= 0; p -= 8) {
        if (t < 256) hist[t] = 0;
        __syncthreads();
        unsigned int mask = (p == 24) ? 0u : (0xFFFFFFFFu << (p + 8));
        for (int i = t; i < V; i += 1024) {
            unsigned int u = mono_map(row[i]);
            if ((u & mask) == pref)
                atomicAdd(&hist[(u >> p) & 255u], 1u);
        }
        __syncthreads();
        if (t == 0) {
            int cum = 0, sel = 0;
            for (int bb = 255; bb >= 0; --bb) {
                int c = (int)hist[bb];
                if (cum + c >= kneed) { sel = bb; break; }
                cum += c;
            }
            sh_pref  = pref | ((unsigned int)sel << p);
            sh_kneed = kneed - cum;
        }
        __syncthreads();
        pref  = sh_pref;
        kneed = sh_kneed;
        __syncthreads();
    }

    const unsigned int T = pref;            // exact 64th-largest mapped value
    if (t == 0) { sh_nA = 0; sh_nE = 0; }
    __syncthreads();
    for (int i = t; i < V; i += 1024) {
        unsigned int u = mono_map(row[i]);
        if (u > T) {
            unsigned int pos = atomicAdd(&sh_nA, 1u);
            if (pos < 64) key[pos] = ((unsigned long long)(~u) << 32) | (unsigned int)i;
        } else if (u == T) {
            unsigned int pos = atomicAdd(&sh_nE, 1u);
            if (pos < 256) eqIdx[pos] = i;
        }
    }
    __syncthreads();
    const int nA = (int)sh_nA;              // < 64 by radix invariant
    const int nE = (int)sh_nE;
    if (t < 256 && t >= min(nE, 256)) eqIdx[t] = 0x7fffffff;
    __syncthreads();
    if (nE > 1) {                            // sort tie indices ascending
        for (int k = 2; k <= 256; k <<= 1)
            for (int j = k >> 1; j > 0; j >>= 1) {
                if (t < 256) {
                    int ixj = t ^ j;
                    if (ixj > t) {
                        int a = eqIdx[t], c = eqIdx[ixj];
                        bool up = ((t & k) == 0);
                        if ((a > c) == up) { eqIdx[t] = c; eqIdx[ixj] = a; }
                    }
                }
                __syncthreads();
            }
    }
    if (t < kneed)
        key[nA + t] = ((unsigned long long)(~T) << 32) | (unsigned int)eqIdx[t];
    __syncthreads();
    // sort 64 keys ascending == (value desc, idx asc)
    for (int k = 2; k <= 64; k <<= 1)
        for (int j = k >> 1; j > 0; j >>= 1) {
            if (t < 64) {
                int ixj = t ^ j;
                if (ixj > t) {
                    unsigned long long a = key[t], c = key[ixj];
                    bool up = ((t & k) == 0);
                    if ((a > c) == up) { key[t] = c; key[ixj] = a; }
                }
            }
            __syncthreads();
        }
    if (t < KSEL) {
        int idx = (int)(unsigned int)(key[t] & 0xFFFFFFFFull);
        idxout[b*KSEL + t]  = idx;
        out_idx[b*KSEL + t] = (float)idx;
    }
}

// ---------- gather selected key rows ----------
__global__ void gather_kernel(const int* __restrict__ idx, const float* __restrict__ Kmat,
                              float* __restrict__ out_sel)
{
    int j = blockIdx.x & 63, b = blockIdx.x >> 6, t = threadIdx.x;
    int sel = idx[b*KSEL + j];
    float4 v = *reinterpret_cast<const float4*>(Kmat + (size_t)sel * D + t*4);
    *reinterpret_cast<float4*>(out_sel + ((size_t)(b*KSEL + j)) * D + t*4) = v;
}

// =====================================================================
// FALLBACK PATH (round-2, known-good) — used when ws_size is too small
// =====================================================================
#define BMT 128
#define BVT 128
#define NSTEP (D/32)

__global__ void row_invnorm_kernel(const float* __restrict__ x, float* __restrict__ inv, int rows)
{
    int wid  = (blockIdx.x * blockDim.x + threadIdx.x) >> 6;
    int lane = threadIdx.x & 63;
    if (wid >= rows) return;
    const float* r = x + (size_t)wid * D;
    float ss = 0.f;
    #pragma unroll
    for (int s = 0; s < 3; ++s) {
        float4 v = *reinterpret_cast<const float4*>(r + s*256 + lane*4);
        ss += v.x*v.x + v.y*v.y + v.z*v.z + v.w*v.w;
    }
    #pragma unroll
    for (int off = 32; off > 0; off >>= 1)
        ss += __shfl_xor(ss, off, 64);
    if (lane == 0) inv[wid] = 1.0f / fmaxf(sqrtf(ss), 1e-12f);
}

__global__ void compute_gq_kernel(const float* __restrict__ q, const float* __restrict__ invq,
                                  float* __restrict__ gq)
{
    int t = blockIdx.x * blockDim.x + threadIdx.x;
    if (t >= BQ*D) return;
    int b = t / D, d = t - b*D;
    float acc = 0.f;
    const float* qb = q + (size_t)b * NQ * D + d;
    const float* iq = invq + b*NQ;
    for (int n = 0; n < NQ; ++n)
        acc += iq[n] * qb[(size_t)n*D];
    gq[t] = acc * (1.0f/(float)NQ);
}

__device__ __forceinline__ void split8(float4 a, float4 b, uint4& hi, uint4& lo)
{
    unsigned int h0,h1,h2,h3,h4,h5,h6,h7, l0,l1,l2,l3,l4,l5,l6,l7;
    split1(a.x,h0,l0); split1(a.y,h1,l1); split1(a.z,h2,l2); split1(a.w,h3,l3);
    split1(b.x,h4,l4); split1(b.y,h5,l5); split1(b.z,h6,l6); split1(b.w,h7,l7);
    hi.x = h0 | (h1<<16); hi.y = h2 | (h3<<16); hi.z = h4 | (h5<<16); hi.w = h6 | (h7<<16);
    lo.x = l0 | (l1<<16); lo.y = l2 | (l3<<16); lo.z = l4 | (l5<<16); lo.w = l6 | (l7<<16);
}

__global__ __launch_bounds__(256)
void mfma_gemm_maxpool(const float* __restrict__ Q, const float* __restrict__ Kmat,
                       const float* __restrict__ invq, const float* __restrict__ invk,
                       float* __restrict__ partial, int V, int Vp)
{
    __shared__ __align__(16) unsigned short lds[16384];
    const int t    = threadIdx.x;
    const int lane = t & 63;
    const int w    = t >> 6;
    const int wr   = w >> 1;
    const int wc   = w & 1;
    const int v0   = blockIdx.x * BVT;
    const int m0   = blockIdx.y * BMT;

    const int srow = t >> 1;
    const int scol = (t & 1) * 16;
    const int c0   = (t & 1) * 2;
    const unsigned int ps0 = (c0     + (srow >> 1)) & 3;
    const unsigned int ps1 = (c0 + 1 + (srow >> 1)) & 3;
    const unsigned int wO0 = srow*32 + ps0*8;
    const unsigned int wO1 = srow*32 + ps1*8;

    const float* Ap = Q + (size_t)(m0 + srow) * D + scol;
    int vrow = v0 + srow; if (vrow > V-1) vrow = V-1;
    const float* Bp = Kmat + (size_t)vrow * D + scol;

    const int lr = lane & 15, kg = lane >> 4;
    const int arowb = wr*64 + lr;
    const int browb = wc*64 + lr;
    const unsigned int slotA = (kg + (arowb >> 1)) & 3;
    const unsigned int slotB = (kg + (browb >> 1)) & 3;
    const unsigned int offA = arowb*32 + slotA*8;
    const unsigned int offB = browb*32 + slotB*8;

    f32x4 acc[4][4];
    #pragma unroll
    for (int i = 0; i < 4; ++i)
        #pragma unroll
        for (int j = 0; j < 4; ++j)
            acc[i][j] = f32x4{0.f,0.f,0.f,0.f};

    float4 ra0,ra1,ra2,ra3, rb0,rb1,rb2,rb3;
    #define LOADSTEP(s_) do { \
        const float* ap_ = Ap + (s_)*32; const float* bp_ = Bp + (s_)*32; \
        ra0 = *(const float4*)(ap_);    ra1 = *(const float4*)(ap_+4); \
        ra2 = *(const float4*)(ap_+8);  ra3 = *(const float4*)(ap_+12); \
        rb0 = *(const float4*)(bp_);    rb1 = *(const float4*)(bp_+4); \
        rb2 = *(const float4*)(bp_+8);  rb3 = *(const float4*)(bp_+12); \
    } while(0)

    LOADSTEP(0);
    for (int s = 0; s < NSTEP; ++s) {
        uint4 ah0,al0, ah1,al1, bh0,bl0, bh1,bl1;
        split8(ra0,ra1, ah0,al0); split8(ra2,ra3, ah1,al1);
        split8(rb0,rb1, bh0,bl0); split8(rb2,rb3, bh1,bl1);
        __syncthreads();
        *(uint4*)&lds[        wO0] = ah0;  *(uint4*)&lds[ 4096 + wO0] = al0;
        *(uint4*)&lds[        wO1] = ah1;  *(uint4*)&lds[ 4096 + wO1] = al1;
        *(uint4*)&lds[ 8192 + wO0] = bh0;  *(uint4*)&lds[12288 + wO0] = bl0;
        *(uint4*)&lds[ 8192 + wO1] = bh1;  *(uint4*)&lds[12288 + wO1] = bl1;
        if (s + 1 < NSTEP) LOADSTEP(s + 1);
        __syncthreads();

        bf16x8 Ah[4], Al[4], Bh[4], Bl[4];
        #pragma unroll
        for (int fm = 0; fm < 4; ++fm) {
            unsigned int o = offA + fm*512;
            Ah[fm] = *(const bf16x8*)&lds[o];
            Al[fm] = *(const bf16x8*)&lds[4096 + o];
        }
        #pragma unroll
        for (int fv = 0; fv < 4; ++fv) {
            unsigned int o = offB + fv*512;
            Bh[fv] = *(const bf16x8*)&lds[8192 + o];
            Bl[fv] = *(const bf16x8*)&lds[12288 + o];
        }
        #pragma unroll
        for (int fm = 0; fm < 4; ++fm)
            #pragma unroll
            for (int fv = 0; fv < 4; ++fv) {
                acc[fm][fv] = __builtin_amdgcn_mfma_f32_16x16x32_bf16(Ah[fm], Bh[fv], acc[fm][fv], 0,0,0);
                acc[fm][fv] = __builtin_amdgcn_mfma_f32_16x16x32_bf16(Ah[fm], Bl[fv], acc[fm][fv], 0,0,0);
                acc[fm][fv] = __builtin_amdgcn_mfma_f32_16x16x32_bf16(Al[fm], Bh[fv], acc[fm][fv], 0,0,0);
            }
    }
    #undef LOADSTEP

    __syncthreads();
    float* red = (float*)lds;
    float iq[4][4];
    #pragma unroll
    for (int fm = 0; fm < 4; ++fm)
        #pragma unroll
        for (int r = 0; r < 4; ++r)
            iq[fm][r] = invq[m0 + wr*64 + fm*16 + kg*4 + r];
    #pragma unroll
    for (int fv = 0; fv < 4; ++fv) {
        float tm = -INFINITY;
        #pragma unroll
        for (int fm = 0; fm < 4; ++fm)
            #pragma unroll
            for (int r = 0; r < 4; ++r)
                tm = fmaxf(tm, acc[fm][fv][r] * iq[fm][r]);
        tm = fmaxf(tm, __shfl_xor(tm, 16, 64));
        tm = fmaxf(tm, __shfl_xor(tm, 32, 64));
        if (lane < 16) red[wr*128 + wc*64 + fv*16 + lane] = tm;
    }
    __syncthreads();
    if (t < 128) {
        int v = v0 + t;
        if (v < V)
            partial[(size_t)blockIdx.y * Vp + v] = fmaxf(red[t], red[128 + t]) * invk[v];
    }
}

__global__ void fused_sim_kernel(const float* __restrict__ Kmat, const float* __restrict__ invk,
                                 const float* __restrict__ gq, const float* __restrict__ partial,
                                 const float* __restrict__ alpha_raw,
                                 float* __restrict__ out_fused, float* __restrict__ out_alpha,
                                 int V, int Vp)
{
    int wib  = threadIdx.x >> 6;
    int lane = threadIdx.x & 63;
    float alpha = 1.0f / (1.0f + expf(-alpha_raw[0]));
    if (blockIdx.x == 0 && threadIdx.x == 0) out_alpha[0] = alpha;
    int v = blockIdx.x * 4 + wib;
    if (v >= V) return;
    const float* kr = Kmat + (size_t)v * D;
    float accb[BQ] = {0.f,0.f,0.f,0.f};
    #pragma unroll
    for (int s = 0; s < 3; ++s) {
        float4 kv = *reinterpret_cast<const float4*>(kr + s*256 + lane*4);
        #pragma unroll
        for (int b = 0; b < BQ; ++b) {
            float4 gv = *reinterpret_cast<const float4*>(gq + b*D + s*256 + lane*4);
            accb[b] += gv.x*kv.x + gv.y*kv.y + gv.z*kv.z + gv.w*kv.w;
        }
    }
    #pragma unroll
    for (int b = 0; b < BQ; ++b)
        #pragma unroll
        for (int off = 32; off > 0; off >>= 1)
            accb[b] += __shfl_xor(accb[b], off, 64);
    if (lane < BQ) {
        int b = lane;
        float node = partial[(size_t)(b*4+0)*Vp + v];
        #pragma unroll
        for (int i = 1; i < 4; ++i)
            node = fmaxf(node, partial[(size_t)(b*4+i)*Vp + v]);
        float graph = accb[b] * invk[v];
        out_fused[(size_t)b*V + v] = alpha*node + (1.0f-alpha)*graph;
    }
}

__global__ __launch_bounds__(1024)
void topk_gather_kernel(const float* __restrict__ fused, const float* __restrict__ Kmat,
                        float* __restrict__ scratch, float* __restrict__ out_sel,
                        float* __restrict__ out_idx, int V, int Vp)
{
    const int b = blockIdx.x, t = threadIdx.x;
    const int lane = t & 63, wid = t >> 6;
    const float* row = fused + (size_t)b * V;
    float* s = scratch + (size_t)b * Vp;
    for (int i = t; i < V; i += 1024) s[i] = row[i];
    __syncthreads();

    const int CH = (V + 1023) / 1024;
    const int lo = t * CH;
    const int hi = min(V, lo + CH);
    float lmax = -INFINITY; int lidx = 0x7fffffff;
    for (int i = lo; i < hi; ++i) { float x = s[i]; if (x > lmax) { lmax = x; lidx = i; } }

    __shared__ float swv[16];
    __shared__ int   swi[16];
    __shared__ int   sbest;

    for (int j = 0; j < KSEL; ++j) {
        float v = lmax; int id = lidx;
        #pragma unroll
        for (int off = 32; off > 0; off >>= 1) {
            float ov = __shfl_xor(v, off, 64);
            int   oi = __shfl_xor(id, off, 64);
            if (ov > v || (ov == v && oi < id)) { v = ov; id = oi; }
        }
        if (lane == 0) { swv[wid] = v; swi[wid] = id; }
        __syncthreads();
        if (t == 0) {
            float bv = swv[0]; int bi = swi[0];
            for (int x = 1; x < 16; ++x)
                if (swv[x] > bv || (swv[x] == bv && swi[x] < bi)) { bv = swv[x]; bi = swi[x]; }
            sbest = bi;
            out_idx[b*KSEL + j] = (float)bi;
        }
        __syncthreads();
        const int sel = sbest;
        if (sel >= lo && sel < hi) {
            s[sel] = -INFINITY;
            lmax = -INFINITY; lidx = 0x7fffffff;
            for (int i = lo; i < hi; ++i) { float x = s[i]; if (x > lmax) { lmax = x; lidx = i; } }
        }
        if (t < 192) {
            float4 kv = *reinterpret_cast<const float4*>(&Kmat[(size_t)sel * D + t*4]);
            *reinterpret_cast<float4*>(&out_sel[((size_t)b*KSEL + j)*D + t*4]) = kv;
        }
        __syncthreads();
    }
}

// =====================================================================
extern "C" void kernel_launch(void* const* d_in, const int* in_sizes, int n_in,
                              void* d_out, int out_size, void* d_ws, size_t ws_size,
                              hipStream_t stream)
{
    const float* q         = (const float*)d_in[0];
    const float* kemb      = (const float*)d_in[1];
    const float* alpha_raw = (const float*)d_in[2];
    int V = in_sizes[1] / D;

    float* out_sel   = (float*)d_out;
    float* out_idx   = out_sel + BQ*KSEL*D;
    float* out_fused = out_idx + BQ*KSEL;
    float* out_alpha = out_fused + (size_t)BQ*V;

    // ---------- fast-path workspace layout ----------
    size_t Vp = (size_t)((V + 255) & ~255);
    float* ws      = (float*)d_ws;
    float* invk    = ws;                               // Vp
    float* invq    = invk + Vp;                        // M_TOTAL
    float* pmax    = invq + M_TOTAL;                   // 8*Vp
    float* psum    = pmax + 8*Vp;                      // 8*Vp
    float* scratch = psum + 8*Vp;                      // 4*Vp (unused in fast path)
    int*   idxbuf  = (int*)(scratch + 4*Vp);           // 256
    unsigned short* Qsp = (unsigned short*)(idxbuf + 256);      // M_TOTAL*1536
    unsigned short* Ksp = Qsp + (size_t)M_TOTAL * (2*D);        // Vp*1536
    size_t need = (size_t)((char*)(Ksp + Vp*(2*D)) - (char*)d_ws);

    if (ws_size >= need) {
        // ---------- FAST PATH ----------
        split_invnorm_kernel<<<M_TOTAL/4, 256, 0, stream>>>(q, Qsp, invq, M_TOTAL, M_TOTAL);
        split_invnorm_kernel<<<(int)(Vp/4), 256, 0, stream>>>(kemb, Ksp, invk, V, (int)Vp);

        hipFuncSetAttribute(reinterpret_cast<const void*>(fast_gemm),
                            hipFuncAttributeMaxDynamicSharedMemorySize, 3*SLOT_SZ);

        int gx = (int)(Vp / GBN);
        fast_gemm<<<gx*8, 512, 3*SLOT_SZ, stream>>>(Qsp, Ksp, invq, pmax, psum, (int)Vp, gx);

        blend_kernel<<<(V + 255)/256, 256, 0, stream>>>(pmax, psum, invk, alpha_raw,
                                                        out_fused, out_alpha, V, (int)Vp);
        topk_radix_kernel<<<BQ, 1024, 0, stream>>>(out_fused, idxbuf, out_idx, V);
        gather_kernel<<<BQ*KSEL, 192, 0, stream>>>(idxbuf, kemb, out_sel);
    } else {
        // ---------- FALLBACK (round-2) ----------
        int Vp2 = (V + 127) & ~127;
        float* f_invk    = ws;
        float* f_invq    = f_invk + Vp2;
        float* f_gq      = f_invq + M_TOTAL;
        float* f_partial = f_gq + BQ*D;
        float* f_scratch = f_partial + (size_t)16*Vp2;

        row_invnorm_kernel<<<(V + 3)/4, 256, 0, stream>>>(kemb, f_invk, V);
        row_invnorm_kernel<<<(M_TOTAL + 3)/4, 256, 0, stream>>>(q, f_invq, M_TOTAL);
        compute_gq_kernel<<<(BQ*D + 255)/256, 256, 0, stream>>>(q, f_invq, f_gq);

        dim3 g(Vp2 / BVT, M_TOTAL / BMT);
        mfma_gemm_maxpool<<<g, 256, 0, stream>>>(q, kemb, f_invq, f_invk, f_partial, V, Vp2);

        fused_sim_kernel<<<(V + 3)/4, 256, 0, stream>>>(kemb, f_invk, f_gq, f_partial, alpha_raw,
                                                        out_fused, out_alpha, V, Vp2);
        topk_gather_kernel<<<BQ, 1024, 0, stream>>>(out_fused, kemb, f_scratch, out_sel, out_idx, V, Vp2);
    }
}

// Round 5
// 523.498 us; speedup vs baseline: 6.4566x; 1.0821x over previous
//
#include <hip/hip_runtime.h>
#include <hip/hip_bf16.h>
#include <math.h>

#define D 768
#define BQ 4
#define NQ 512
#define M_TOTAL (BQ*NQ)   // 2048
#define KSEL 64

typedef short bf16x8 __attribute__((ext_vector_type(8)));
typedef float f32x4  __attribute__((ext_vector_type(4)));

// ---------- fp32 -> bf16 hi/lo split ----------
__device__ __forceinline__ void split1(float x, unsigned int& h, unsigned int& l)
{
    unsigned int u  = __float_as_uint(x);
    unsigned int hb = (u + 0x7fffu + ((u >> 16) & 1u)) & 0xffff0000u;  // RNE bf16
    h = hb >> 16;
    l = __float_as_uint(x - __uint_as_float(hb)) >> 16;                 // truncated residual
}

// =====================================================================
// FAST PATH
// =====================================================================

// ---------- fused: L2 inv-norm + hi/lo bf16 split, one wave per row ----------
__global__ void split_invnorm_kernel(const float* __restrict__ x, unsigned short* __restrict__ sp,
                                     float* __restrict__ inv, int rows_src, int rows_dst)
{
    int r    = (blockIdx.x * blockDim.x + threadIdx.x) >> 6;
    int lane = threadIdx.x & 63;
    if (r >= rows_dst) return;
    int src = r < rows_src ? r : rows_src - 1;      // clamp pad rows
    const float* row = x + (size_t)src * D;
    unsigned short* dh = sp + (size_t)r * (2*D);
    unsigned short* dl = dh + D;
    float ss = 0.f;
    #pragma unroll
    for (int s = 0; s < 3; ++s) {
        float4 v = *reinterpret_cast<const float4*>(row + s*256 + lane*4);
        ss += v.x*v.x + v.y*v.y + v.z*v.z + v.w*v.w;
        unsigned int h0,h1,h2,h3,l0,l1,l2,l3;
        split1(v.x,h0,l0); split1(v.y,h1,l1); split1(v.z,h2,l2); split1(v.w,h3,l3);
        ushort4 hv = make_ushort4((unsigned short)h0,(unsigned short)h1,(unsigned short)h2,(unsigned short)h3);
        ushort4 lv = make_ushort4((unsigned short)l0,(unsigned short)l1,(unsigned short)l2,(unsigned short)l3);
        *reinterpret_cast<ushort4*>(dh + s*256 + lane*4) = hv;
        *reinterpret_cast<ushort4*>(dl + s*256 + lane*4) = lv;
    }
    #pragma unroll
    for (int off = 32; off > 0; off >>= 1)
        ss += __shfl_xor(ss, off, 64);
    if (lane == 0 && r < rows_src)
        inv[r] = 1.0f / fmaxf(sqrtf(ss), 1e-12f);
}

// ---------- 256x256 4-phase split-bf16 MFMA GEMM, fused max+sum epilogues ----------
// 8 waves (2M x 4N), per-wave 128x64 (8 m-frags x 4 n-frags), BK=32.
// LDS slot: A 256 rows x 128B (hi|lo chunks, XOR-swizzled) = 32KB ; B same = 32KB.
// Double-buffered: 2 x 64KB = 128KB dynamic LDS (1 block/CU).
// Derived waits: per-thread gload queue per K-tile = [B B A0 B B A1 A2 A3];
// vmcnt(6) end-of-phase-1, vmcnt(2) end-of-phase-3, never 0 in steady state.
#define GBM 256
#define GBN 256
#define GBK 32
#define GNT (D/GBK)     // 24
#define SLOT_B_OFF 32768
#define SLOT_SZ 65536

__device__ __forceinline__ void gload16(const unsigned short* g, char* l)
{
    __builtin_amdgcn_global_load_lds((const __attribute__((address_space(1))) void*)g,
                                     (__attribute__((address_space(3))) void*)l, 16, 0, 0);
}

__global__ __launch_bounds__(512, 2)
void fast_gemm(const unsigned short* __restrict__ Qsp, const unsigned short* __restrict__ Ksp,
               const float* __restrict__ invq, float* __restrict__ pmax, float* __restrict__ psum,
               int Vp, int gx)
{
    extern __shared__ char smem[];

    const int t    = threadIdx.x;
    const int lane = t & 63;
    const int w    = t >> 6;         // 0..7
    const int wr   = w >> 2;         // 0..1 (m)
    const int wc   = w & 3;          // 0..3 (v)

    // XCD-aware swizzle, m-dim fastest (8 consecutive u share one B panel)
    int lid = blockIdx.x;
    int u   = (lid & 7) * gx + (lid >> 3);
    const int by = u & 7;
    const int bx = u >> 3;
    const int m0 = by * GBM;
    const int v0 = bx * GBN;

    // ---- staging: per-lane pre-swizzled global source ----
    const int lrow = lane >> 3;                    // dest row within 8-row group
    const int cc   = (lane & 7) ^ lrow;            // logical chunk at this lane's slot
    const size_t goff = (size_t)lrow * (2*D) + (size_t)(cc >> 2) * D + (size_t)(cc & 3) * 8;

    // A gloads: group j covers LDS rows {j*32..j*32+31} U {128+j*32..+31} (8 gloads, 1/wave)
    const int rAbase = ((w & 3) << 3) + ((w >> 2) << 7);   // + j*32
    // B gloads: wave w covers rows w*32 + j*8, j=0..3
    const int rBbase = w * 32;

    const unsigned short* gAsrc = Qsp + (size_t)(m0 + rAbase) * (2*D) + goff;
    const unsigned short* gBsrc = Ksp + (size_t)(v0 + rBbase) * (2*D) + goff;

    #define SAk(k_, sl_, j_) gload16(gAsrc + (k_) + (size_t)(j_)*32*(2*D), (sl_) + (rAbase + (j_)*32)*128)
    #define SBk(k_, sl_, j_) gload16(gBsrc + (k_) + (size_t)(j_)*8 *(2*D), (sl_) + SLOT_B_OFF + (rBbase + (j_)*8)*128)

    // ---- fragment read offsets (swizzle matches staging) ----
    const int l15 = lane & 15, kg = lane >> 4;
    const int sHi = ((kg    ) ^ (lane & 7)) * 16;
    const int sLo = ((kg + 4) ^ (lane & 7)) * 16;
    const int offA = (wr*128 + l15) * 128;               // + mf*2048 + sHi/sLo
    const int offB = SLOT_B_OFF + (wc*64 + l15) * 128;   // + nf*2048 + sHi/sLo

    f32x4 acc[8][4];
    #pragma unroll
    for (int i = 0; i < 8; ++i)
        #pragma unroll
        for (int j = 0; j < 4; ++j)
            acc[i][j] = f32x4{0.f,0.f,0.f,0.f};

    bf16x8 Bh[4], Bl[4];

    char* sl0 = smem;
    char* sl1 = smem + SLOT_SZ;

    // ---- prologue: stage tile 0 in steady-state queue order ----
    SBk(0, sl0, 0); SBk(0, sl0, 1); SAk(0, sl0, 0);
    SBk(0, sl0, 2); SBk(0, sl0, 3); SAk(0, sl0, 1);
    SAk(0, sl0, 2); SAk(0, sl0, 3);
    asm volatile("s_waitcnt vmcnt(2)" ::: "memory");   // B x4 + A0 + A1 resident
    __builtin_amdgcn_s_barrier();

    #define PHASE(p_, STG, VMW) do {                                                         \
        bf16x8 Ah0 = *(const bf16x8*)(scur + offA + (2*(p_)  )*2048 + sHi);                  \
        bf16x8 Al0 = *(const bf16x8*)(scur + offA + (2*(p_)  )*2048 + sLo);                  \
        bf16x8 Ah1 = *(const bf16x8*)(scur + offA + (2*(p_)+1)*2048 + sHi);                  \
        bf16x8 Al1 = *(const bf16x8*)(scur + offA + (2*(p_)+1)*2048 + sLo);                  \
        STG;                                                                                 \
        __builtin_amdgcn_s_barrier();                                                        \
        asm volatile("s_waitcnt lgkmcnt(0)" ::: "memory");                                   \
        __builtin_amdgcn_s_setprio(1);                                                       \
        _Pragma("unroll")                                                                    \
        for (int nf = 0; nf < 4; ++nf) {                                                     \
            acc[2*(p_)  ][nf] = __builtin_amdgcn_mfma_f32_16x16x32_bf16(Ah0, Bh[nf], acc[2*(p_)  ][nf], 0,0,0); \
            acc[2*(p_)+1][nf] = __builtin_amdgcn_mfma_f32_16x16x32_bf16(Ah1, Bh[nf], acc[2*(p_)+1][nf], 0,0,0); \
        }                                                                                    \
        _Pragma("unroll")                                                                    \
        for (int nf = 0; nf < 4; ++nf) {                                                     \
            acc[2*(p_)  ][nf] = __builtin_amdgcn_mfma_f32_16x16x32_bf16(Ah0, Bl[nf], acc[2*(p_)  ][nf], 0,0,0); \
            acc[2*(p_)+1][nf] = __builtin_amdgcn_mfma_f32_16x16x32_bf16(Ah1, Bl[nf], acc[2*(p_)+1][nf], 0,0,0); \
        }                                                                                    \
        _Pragma("unroll")                                                                    \
        for (int nf = 0; nf < 4; ++nf) {                                                     \
            acc[2*(p_)  ][nf] = __builtin_amdgcn_mfma_f32_16x16x32_bf16(Al0, Bh[nf], acc[2*(p_)  ][nf], 0,0,0); \
            acc[2*(p_)+1][nf] = __builtin_amdgcn_mfma_f32_16x16x32_bf16(Al1, Bh[nf], acc[2*(p_)+1][nf], 0,0,0); \
        }                                                                                    \
        __builtin_amdgcn_s_setprio(0);                                                       \
        VMW;                                                                                 \
        __builtin_amdgcn_s_barrier();                                                        \
    } while(0)

    for (int T = 0; T < GNT; ++T) {
        const bool st = (T + 1 < GNT);
        char* scur = (T & 1) ? sl1 : sl0;
        char* snxt = (T & 1) ? sl0 : sl1;
        const int k1 = (T + 1) * GBK;

        // phase 0: B frags (once per K-step) + A quadrant 0
        #pragma unroll
        for (int nf = 0; nf < 4; ++nf) {
            Bh[nf] = *(const bf16x8*)(scur + offB + nf*2048 + sHi);
            Bl[nf] = *(const bf16x8*)(scur + offB + nf*2048 + sLo);
        }
        PHASE(0, { if (st) { SBk(k1, snxt, 0); SBk(k1, snxt, 1); SAk(k1, snxt, 0); } }, );
        // phase 1 (end: free A2,A3 of current tile — counted, not 0, when staging)
        PHASE(1, { if (st) { SBk(k1, snxt, 2); SBk(k1, snxt, 3); SAk(k1, snxt, 1); } },
                 { if (st) asm volatile("s_waitcnt vmcnt(6)" ::: "memory");
                   else    asm volatile("s_waitcnt vmcnt(0)" ::: "memory"); });
        // phase 2
        PHASE(2, { if (st) SAk(k1, snxt, 2); }, );
        // phase 3 (end: free B x4 + A0 + A1 of NEXT tile)
        PHASE(3, { if (st) SAk(k1, snxt, 3); },
                 { if (st) asm volatile("s_waitcnt vmcnt(2)" ::: "memory"); });
    }
    #undef PHASE
    #undef SAk
    #undef SBk

    // ---- epilogue: per-column max (node) and sum (graph), invq-scaled ----
    __syncthreads();
    float iq[32];
    #pragma unroll
    for (int mf = 0; mf < 8; ++mf)
        #pragma unroll
        for (int r = 0; r < 4; ++r)
            iq[mf*4+r] = invq[m0 + wr*128 + mf*16 + kg*4 + r];

    float* redm = (float*)smem;        // [2][256]
    float* reds = redm + 512;          // [2][256]
    #pragma unroll
    for (int nf = 0; nf < 4; ++nf) {
        float pmv = -INFINITY, psv = 0.f;
        #pragma unroll
        for (int mf = 0; mf < 8; ++mf)
            #pragma unroll
            for (int r = 0; r < 4; ++r) {
                float x = acc[mf][nf][r] * iq[mf*4+r];
                pmv = fmaxf(pmv, x);
                psv += x;
            }
        pmv = fmaxf(pmv, __shfl_xor(pmv, 16, 64));
        pmv = fmaxf(pmv, __shfl_xor(pmv, 32, 64));
        psv += __shfl_xor(psv, 16, 64);
        psv += __shfl_xor(psv, 32, 64);
        if (lane < 16) {
            redm[wr*256 + wc*64 + nf*16 + l15] = pmv;
            reds[wr*256 + wc*64 + nf*16 + l15] = psv;
        }
    }
    __syncthreads();
    if (t < 256) {
        pmax[(size_t)by * Vp + v0 + t] = fmaxf(redm[t], redm[256+t]);
        psum[(size_t)by * Vp + v0 + t] = reds[t] + reds[256+t];
    }
}

// ---------- blend: node max over batch tiles + graph from psum ----------
__global__ void blend_kernel(const float* __restrict__ pmax, const float* __restrict__ psum,
                             const float* __restrict__ invk, const float* __restrict__ alpha_raw,
                             float* __restrict__ out_fused, float* __restrict__ out_alpha,
                             int V, int Vp)
{
    int v = blockIdx.x * 256 + threadIdx.x;
    float alpha = 1.0f / (1.0f + expf(-alpha_raw[0]));
    if (blockIdx.x == 0 && threadIdx.x == 0) out_alpha[0] = alpha;
    if (v >= V) return;
    float ik = invk[v];
    #pragma unroll
    for (int b = 0; b < BQ; ++b) {
        float nm = fmaxf(pmax[(size_t)(2*b)*Vp + v], pmax[(size_t)(2*b+1)*Vp + v]) * ik;
        float gs = (psum[(size_t)(2*b)*Vp + v] + psum[(size_t)(2*b+1)*Vp + v]) * ik * (1.0f/(float)NQ);
        out_fused[(size_t)b*V + v] = alpha*nm + (1.0f-alpha)*gs;
    }
}

// ---------- per-batch top-64 via 4-pass radix select + bitonic order ----------
__device__ __forceinline__ unsigned int mono_map(float f)
{
    unsigned int u = __float_as_uint(f);
    return u ^ ((u & 0x80000000u) ? 0xFFFFFFFFu : 0x80000000u);
}

__global__ __launch_bounds__(1024)
void topk_radix_kernel(const float* __restrict__ fused,
                       int* __restrict__ idxout, float* __restrict__ out_idx, int V)
{
    const int b = blockIdx.x, t = threadIdx.x;
    const float* row = fused + (size_t)b * V;

    __shared__ unsigned int hist[256];
    __shared__ unsigned int sh_pref;
    __shared__ int sh_kneed;
    __shared__ unsigned int sh_nA, sh_nE;
    __shared__ unsigned long long key[64];
    __shared__ int eqIdx[256];

    unsigned int pref = 0;
    int kneed = KSEL;
    #pragma unroll
    for (int p = 24; p >= 0; p -= 8) {
        if (t < 256) hist[t] = 0;
        __syncthreads();
        unsigned int mask = (p == 24) ? 0u : (0xFFFFFFFFu << (p + 8));
        for (int i = t; i < V; i += 1024) {
            unsigned int u = mono_map(row[i]);
            if ((u & mask) == pref)
                atomicAdd(&hist[(u >> p) & 255u], 1u);
        }
        __syncthreads();
        if (t == 0) {
            int cum = 0, sel = 0;
            for (int bb = 255; bb >= 0; --bb) {
                int c = (int)hist[bb];
                if (cum + c >= kneed) { sel = bb; break; }
                cum += c;
            }
            sh_pref  = pref | ((unsigned int)sel << p);
            sh_kneed = kneed - cum;
        }
        __syncthreads();
        pref  = sh_pref;
        kneed = sh_kneed;
        __syncthreads();
    }

    const unsigned int T = pref;            // exact 64th-largest mapped value
    if (t == 0) { sh_nA = 0; sh_nE = 0; }
    __syncthreads();
    for (int i = t; i < V; i += 1024) {
        unsigned int u = mono_map(row[i]);
        if (u > T) {
            unsigned int pos = atomicAdd(&sh_nA, 1u);
            if (pos < 64) key[pos] = ((unsigned long long)(~u) << 32) | (unsigned int)i;
        } else if (u == T) {
            unsigned int pos = atomicAdd(&sh_nE, 1u);
            if (pos < 256) eqIdx[pos] = i;
        }
    }
    __syncthreads();
    const int nA = (int)sh_nA;              // < 64 by radix invariant
    const int nE = (int)sh_nE;
    if (t < 256 && t >= min(nE, 256)) eqIdx[t] = 0x7fffffff;
    __syncthreads();
    if (nE > 1) {                            // sort tie indices ascending
        for (int k = 2; k <= 256; k <<= 1)
            for (int j = k >> 1; j > 0; j >>= 1) {
                if (t < 256) {
                    int ixj = t ^ j;
                    if (ixj > t) {
                        int a = eqIdx[t], c = eqIdx[ixj];
                        bool up = ((t & k) == 0);
                        if ((a > c) == up) { eqIdx[t] = c; eqIdx[ixj] = a; }
                    }
                }
                __syncthreads();
            }
    }
    if (t < kneed)
        key[nA + t] = ((unsigned long long)(~T) << 32) | (unsigned int)eqIdx[t];
    __syncthreads();
    // sort 64 keys ascending == (value desc, idx asc)
    for (int k = 2; k <= 64; k <<= 1)
        for (int j = k >> 1; j > 0; j >>= 1) {
            if (t < 64) {
                int ixj = t ^ j;
                if (ixj > t) {
                    unsigned long long a = key[t], c = key[ixj];
                    bool up = ((t & k) == 0);
                    if ((a > c) == up) { key[t] = c; key[ixj] = a; }
                }
            }
            __syncthreads();
        }
    if (t < KSEL) {
        int idx = (int)(unsigned int)(key[t] & 0xFFFFFFFFull);
        idxout[b*KSEL + t]  = idx;
        out_idx[b*KSEL + t] = (float)idx;
    }
}

// ---------- gather selected key rows ----------
__global__ void gather_kernel(const int* __restrict__ idx, const float* __restrict__ Kmat,
                              float* __restrict__ out_sel)
{
    int j = blockIdx.x & 63, b = blockIdx.x >> 6, t = threadIdx.x;
    int sel = idx[b*KSEL + j];
    float4 v = *reinterpret_cast<const float4*>(Kmat + (size_t)sel * D + t*4);
    *reinterpret_cast<float4*>(out_sel + ((size_t)(b*KSEL + j)) * D + t*4) = v;
}

// =====================================================================
// FALLBACK PATH (round-2, known-good) — used when ws_size is too small
// =====================================================================
#define BMT 128
#define BVT 128
#define NSTEP (D/32)

__global__ void row_invnorm_kernel(const float* __restrict__ x, float* __restrict__ inv, int rows)
{
    int wid  = (blockIdx.x * blockDim.x + threadIdx.x) >> 6;
    int lane = threadIdx.x & 63;
    if (wid >= rows) return;
    const float* r = x + (size_t)wid * D;
    float ss = 0.f;
    #pragma unroll
    for (int s = 0; s < 3; ++s) {
        float4 v = *reinterpret_cast<const float4*>(r + s*256 + lane*4);
        ss += v.x*v.x + v.y*v.y + v.z*v.z + v.w*v.w;
    }
    #pragma unroll
    for (int off = 32; off > 0; off >>= 1)
        ss += __shfl_xor(ss, off, 64);
    if (lane == 0) inv[wid] = 1.0f / fmaxf(sqrtf(ss), 1e-12f);
}

__global__ void compute_gq_kernel(const float* __restrict__ q, const float* __restrict__ invq,
                                  float* __restrict__ gq)
{
    int t = blockIdx.x * blockDim.x + threadIdx.x;
    if (t >= BQ*D) return;
    int b = t / D, d = t - b*D;
    float acc = 0.f;
    const float* qb = q + (size_t)b * NQ * D + d;
    const float* iq = invq + b*NQ;
    for (int n = 0; n < NQ; ++n)
        acc += iq[n] * qb[(size_t)n*D];
    gq[t] = acc * (1.0f/(float)NQ);
}

__device__ __forceinline__ void split8(float4 a, float4 b, uint4& hi, uint4& lo)
{
    unsigned int h0,h1,h2,h3,h4,h5,h6,h7, l0,l1,l2,l3,l4,l5,l6,l7;
    split1(a.x,h0,l0); split1(a.y,h1,l1); split1(a.z,h2,l2); split1(a.w,h3,l3);
    split1(b.x,h4,l4); split1(b.y,h5,l5); split1(b.z,h6,l6); split1(b.w,h7,l7);
    hi.x = h0 | (h1<<16); hi.y = h2 | (h3<<16); hi.z = h4 | (h5<<16); hi.w = h6 | (h7<<16);
    lo.x = l0 | (l1<<16); lo.y = l2 | (l3<<16); lo.z = l4 | (l5<<16); lo.w = l6 | (l7<<16);
}

__global__ __launch_bounds__(256)
void mfma_gemm_maxpool(const float* __restrict__ Q, const float* __restrict__ Kmat,
                       const float* __restrict__ invq, const float* __restrict__ invk,
                       float* __restrict__ partial, int V, int Vp)
{
    __shared__ __align__(16) unsigned short lds[16384];
    const int t    = threadIdx.x;
    const int lane = t & 63;
    const int w    = t >> 6;
    const int wr   = w >> 1;
    const int wc   = w & 1;
    const int v0   = blockIdx.x * BVT;
    const int m0   = blockIdx.y * BMT;

    const int srow = t >> 1;
    const int scol = (t & 1) * 16;
    const int c0   = (t & 1) * 2;
    const unsigned int ps0 = (c0     + (srow >> 1)) & 3;
    const unsigned int ps1 = (c0 + 1 + (srow >> 1)) & 3;
    const unsigned int wO0 = srow*32 + ps0*8;
    const unsigned int wO1 = srow*32 + ps1*8;

    const float* Ap = Q + (size_t)(m0 + srow) * D + scol;
    int vrow = v0 + srow; if (vrow > V-1) vrow = V-1;
    const float* Bp = Kmat + (size_t)vrow * D + scol;

    const int lr = lane & 15, kg = lane >> 4;
    const int arowb = wr*64 + lr;
    const int browb = wc*64 + lr;
    const unsigned int slotA = (kg + (arowb >> 1)) & 3;
    const unsigned int slotB = (kg + (browb >> 1)) & 3;
    const unsigned int offA = arowb*32 + slotA*8;
    const unsigned int offB = browb*32 + slotB*8;

    f32x4 acc[4][4];
    #pragma unroll
    for (int i = 0; i < 4; ++i)
        #pragma unroll
        for (int j = 0; j < 4; ++j)
            acc[i][j] = f32x4{0.f,0.f,0.f,0.f};

    float4 ra0,ra1,ra2,ra3, rb0,rb1,rb2,rb3;
    #define LOADSTEP(s_) do { \
        const float* ap_ = Ap + (s_)*32; const float* bp_ = Bp + (s_)*32; \
        ra0 = *(const float4*)(ap_);    ra1 = *(const float4*)(ap_+4); \
        ra2 = *(const float4*)(ap_+8);  ra3 = *(const float4*)(ap_+12); \
        rb0 = *(const float4*)(bp_);    rb1 = *(const float4*)(bp_+4); \
        rb2 = *(const float4*)(bp_+8);  rb3 = *(const float4*)(bp_+12); \
    } while(0)

    LOADSTEP(0);
    for (int s = 0; s < NSTEP; ++s) {
        uint4 ah0,al0, ah1,al1, bh0,bl0, bh1,bl1;
        split8(ra0,ra1, ah0,al0); split8(ra2,ra3, ah1,al1);
        split8(rb0,rb1, bh0,bl0); split8(rb2,rb3, bh1,bl1);
        __syncthreads();
        *(uint4*)&lds[        wO0] = ah0;  *(uint4*)&lds[ 4096 + wO0] = al0;
        *(uint4*)&lds[        wO1] = ah1;  *(uint4*)&lds[ 4096 + wO1] = al1;
        *(uint4*)&lds[ 8192 + wO0] = bh0;  *(uint4*)&lds[12288 + wO0] = bl0;
        *(uint4*)&lds[ 8192 + wO1] = bh1;  *(uint4*)&lds[12288 + wO1] = bl1;
        if (s + 1 < NSTEP) LOADSTEP(s + 1);
        __syncthreads();

        bf16x8 Ah[4], Al[4], Bh[4], Bl[4];
        #pragma unroll
        for (int fm = 0; fm < 4; ++fm) {
            unsigned int o = offA + fm*512;
            Ah[fm] = *(const bf16x8*)&lds[o];
            Al[fm] = *(const bf16x8*)&lds[4096 + o];
        }
        #pragma unroll
        for (int fv = 0; fv < 4; ++fv) {
            unsigned int o = offB + fv*512;
            Bh[fv] = *(const bf16x8*)&lds[8192 + o];
            Bl[fv] = *(const bf16x8*)&lds[12288 + o];
        }
        #pragma unroll
        for (int fm = 0; fm < 4; ++fm)
            #pragma unroll
            for (int fv = 0; fv < 4; ++fv) {
                acc[fm][fv] = __builtin_amdgcn_mfma_f32_16x16x32_bf16(Ah[fm], Bh[fv], acc[fm][fv], 0,0,0);
                acc[fm][fv] = __builtin_amdgcn_mfma_f32_16x16x32_bf16(Ah[fm], Bl[fv], acc[fm][fv], 0,0,0);
                acc[fm][fv] = __builtin_amdgcn_mfma_f32_16x16x32_bf16(Al[fm], Bh[fv], acc[fm][fv], 0,0,0);
            }
    }
    #undef LOADSTEP

    __syncthreads();
    float* red = (float*)lds;
    float iq[4][4];
    #pragma unroll
    for (int fm = 0; fm < 4; ++fm)
        #pragma unroll
        for (int r = 0; r < 4; ++r)
            iq[fm][r] = invq[m0 + wr*64 + fm*16 + kg*4 + r];
    #pragma unroll
    for (int fv = 0; fv < 4; ++fv) {
        float tm = -INFINITY;
        #pragma unroll
        for (int fm = 0; fm < 4; ++fm)
            #pragma unroll
            for (int r = 0; r < 4; ++r)
                tm = fmaxf(tm, acc[fm][fv][r] * iq[fm][r]);
        tm = fmaxf(tm, __shfl_xor(tm, 16, 64));
        tm = fmaxf(tm, __shfl_xor(tm, 32, 64));
        if (lane < 16) red[wr*128 + wc*64 + fv*16 + lane] = tm;
    }
    __syncthreads();
    if (t < 128) {
        int v = v0 + t;
        if (v < V)
            partial[(size_t)blockIdx.y * Vp + v] = fmaxf(red[t], red[128 + t]) * invk[v];
    }
}

__global__ void fused_sim_kernel(const float* __restrict__ Kmat, const float* __restrict__ invk,
                                 const float* __restrict__ gq, const float* __restrict__ partial,
                                 const float* __restrict__ alpha_raw,
                                 float* __restrict__ out_fused, float* __restrict__ out_alpha,
                                 int V, int Vp)
{
    int wib  = threadIdx.x >> 6;
    int lane = threadIdx.x & 63;
    float alpha = 1.0f / (1.0f + expf(-alpha_raw[0]));
    if (blockIdx.x == 0 && threadIdx.x == 0) out_alpha[0] = alpha;
    int v = blockIdx.x * 4 + wib;
    if (v >= V) return;
    const float* kr = Kmat + (size_t)v * D;
    float accb[BQ] = {0.f,0.f,0.f,0.f};
    #pragma unroll
    for (int s = 0; s < 3; ++s) {
        float4 kv = *reinterpret_cast<const float4*>(kr + s*256 + lane*4);
        #pragma unroll
        for (int b = 0; b < BQ; ++b) {
            float4 gv = *reinterpret_cast<const float4*>(gq + b*D + s*256 + lane*4);
            accb[b] += gv.x*kv.x + gv.y*kv.y + gv.z*kv.z + gv.w*kv.w;
        }
    }
    #pragma unroll
    for (int b = 0; b < BQ; ++b)
        #pragma unroll
        for (int off = 32; off > 0; off >>= 1)
            accb[b] += __shfl_xor(accb[b], off, 64);
    if (lane < BQ) {
        int b = lane;
        float node = partial[(size_t)(b*4+0)*Vp + v];
        #pragma unroll
        for (int i = 1; i < 4; ++i)
            node = fmaxf(node, partial[(size_t)(b*4+i)*Vp + v]);
        float graph = accb[b] * invk[v];
        out_fused[(size_t)b*V + v] = alpha*node + (1.0f-alpha)*graph;
    }
}

__global__ __launch_bounds__(1024)
void topk_gather_kernel(const float* __restrict__ fused, const float* __restrict__ Kmat,
                        float* __restrict__ scratch, float* __restrict__ out_sel,
                        float* __restrict__ out_idx, int V, int Vp)
{
    const int b = blockIdx.x, t = threadIdx.x;
    const int lane = t & 63, wid = t >> 6;
    const float* row = fused + (size_t)b * V;
    float* s = scratch + (size_t)b * Vp;
    for (int i = t; i < V; i += 1024) s[i] = row[i];
    __syncthreads();

    const int CH = (V + 1023) / 1024;
    const int lo = t * CH;
    const int hi = min(V, lo + CH);
    float lmax = -INFINITY; int lidx = 0x7fffffff;
    for (int i = lo; i < hi; ++i) { float x = s[i]; if (x > lmax) { lmax = x; lidx = i; } }

    __shared__ float swv[16];
    __shared__ int   swi[16];
    __shared__ int   sbest;

    for (int j = 0; j < KSEL; ++j) {
        float v = lmax; int id = lidx;
        #pragma unroll
        for (int off = 32; off > 0; off >>= 1) {
            float ov = __shfl_xor(v, off, 64);
            int   oi = __shfl_xor(id, off, 64);
            if (ov > v || (ov == v && oi < id)) { v = ov; id = oi; }
        }
        if (lane == 0) { swv[wid] = v; swi[wid] = id; }
        __syncthreads();
        if (t == 0) {
            float bv = swv[0]; int bi = swi[0];
            for (int x = 1; x < 16; ++x)
                if (swv[x] > bv || (swv[x] == bv && swi[x] < bi)) { bv = swv[x]; bi = swi[x]; }
            sbest = bi;
            out_idx[b*KSEL + j] = (float)bi;
        }
        __syncthreads();
        const int sel = sbest;
        if (sel >= lo && sel < hi) {
            s[sel] = -INFINITY;
            lmax = -INFINITY; lidx = 0x7fffffff;
            for (int i = lo; i < hi; ++i) { float x = s[i]; if (x > lmax) { lmax = x; lidx = i; } }
        }
        if (t < 192) {
            float4 kv = *reinterpret_cast<const float4*>(&Kmat[(size_t)sel * D + t*4]);
            *reinterpret_cast<float4*>(&out_sel[((size_t)b*KSEL + j)*D + t*4]) = kv;
        }
        __syncthreads();
    }
}

// =====================================================================
extern "C" void kernel_launch(void* const* d_in, const int* in_sizes, int n_in,
                              void* d_out, int out_size, void* d_ws, size_t ws_size,
                              hipStream_t stream)
{
    const float* q         = (const float*)d_in[0];
    const float* kemb      = (const float*)d_in[1];
    const float* alpha_raw = (const float*)d_in[2];
    int V = in_sizes[1] / D;

    float* out_sel   = (float*)d_out;
    float* out_idx   = out_sel + BQ*KSEL*D;
    float* out_fused = out_idx + BQ*KSEL;
    float* out_alpha = out_fused + (size_t)BQ*V;

    // ---------- fast-path workspace layout ----------
    size_t Vp = (size_t)((V + 255) & ~255);
    float* ws      = (float*)d_ws;
    float* invk    = ws;                               // Vp
    float* invq    = invk + Vp;                        // M_TOTAL
    float* pmax    = invq + M_TOTAL;                   // 8*Vp
    float* psum    = pmax + 8*Vp;                      // 8*Vp
    float* scratch = psum + 8*Vp;                      // 4*Vp (unused in fast path)
    int*   idxbuf  = (int*)(scratch + 4*Vp);           // 256
    unsigned short* Qsp = (unsigned short*)(idxbuf + 256);      // M_TOTAL*1536
    unsigned short* Ksp = Qsp + (size_t)M_TOTAL * (2*D);        // Vp*1536
    size_t need = (size_t)((char*)(Ksp + Vp*(2*D)) - (char*)d_ws);

    if (ws_size >= need) {
        // ---------- FAST PATH ----------
        split_invnorm_kernel<<<M_TOTAL/4, 256, 0, stream>>>(q, Qsp, invq, M_TOTAL, M_TOTAL);
        split_invnorm_kernel<<<(int)(Vp/4), 256, 0, stream>>>(kemb, Ksp, invk, V, (int)Vp);

        hipFuncSetAttribute(reinterpret_cast<const void*>(fast_gemm),
                            hipFuncAttributeMaxDynamicSharedMemorySize, 2*SLOT_SZ);

        int gx = (int)(Vp / GBN);                      // Vp mult of 256
        fast_gemm<<<gx*8, 512, 2*SLOT_SZ, stream>>>(Qsp, Ksp, invq, pmax, psum, (int)Vp, gx);

        blend_kernel<<<(V + 255)/256, 256, 0, stream>>>(pmax, psum, invk, alpha_raw,
                                                        out_fused, out_alpha, V, (int)Vp);
        topk_radix_kernel<<<BQ, 1024, 0, stream>>>(out_fused, idxbuf, out_idx, V);
        gather_kernel<<<BQ*KSEL, 192, 0, stream>>>(idxbuf, kemb, out_sel);
    } else {
        // ---------- FALLBACK (round-2) ----------
        int Vp2 = (V + 127) & ~127;
        float* f_invk    = ws;
        float* f_invq    = f_invk + Vp2;
        float* f_gq      = f_invq + M_TOTAL;
        float* f_partial = f_gq + BQ*D;
        float* f_scratch = f_partial + (size_t)16*Vp2;

        row_invnorm_kernel<<<(V + 3)/4, 256, 0, stream>>>(kemb, f_invk, V);
        row_invnorm_kernel<<<(M_TOTAL + 3)/4, 256, 0, stream>>>(q, f_invq, M_TOTAL);
        compute_gq_kernel<<<(BQ*D + 255)/256, 256, 0, stream>>>(q, f_invq, f_gq);

        dim3 g(Vp2 / BVT, M_TOTAL / BMT);
        mfma_gemm_maxpool<<<g, 256, 0, stream>>>(q, kemb, f_invq, f_invk, f_partial, V, Vp2);

        fused_sim_kernel<<<(V + 3)/4, 256, 0, stream>>>(kemb, f_invk, f_gq, f_partial, alpha_raw,
                                                        out_fused, out_alpha, V, Vp2);
        topk_gather_kernel<<<BQ, 1024, 0, stream>>>(out_fused, kemb, f_scratch, out_sel, out_idx, V, Vp2);
    }
}